// Round 5
// baseline (466.349 us; speedup 1.0000x reference)
//
#include <hip/hip_runtime.h>
#include <math.h>

// HierarchicalAttentionEncoderLayer — inputs f32, outputs f32, internals bf16.
// R5 (= R3/R4 resubmit; two infra timeouts, never measured):
// attn_fused v2 — no K/Q/V LDS staging (direct global, L2-resident),
// 10 KB LDS, __launch_bounds__(256,3) -> 12 waves/CU, full grid resident;
// unrolled pass-3 (no runtime acc indexing); __expf.
#define B_  8
#define S_  512
#define D_  768
#define H_  12
#define DH_ 64
#define FF_ 3072
#define M_  (B_ * S_)   // 4096 rows

typedef unsigned short u16;
typedef unsigned int   u32;
typedef __bf16  bf16x8 __attribute__((ext_vector_type(8)));
typedef float   f32x4  __attribute__((ext_vector_type(4)));
typedef unsigned short u16x4 __attribute__((ext_vector_type(4)));
typedef unsigned int   u32x2 __attribute__((ext_vector_type(2)));

__device__ __forceinline__ float b2f(u16 h) {
    union { u32 u; float f; } v; v.u = ((u32)h) << 16; return v.f;
}
__device__ __forceinline__ u16 f2b(float f) {
    union { u32 u; float f; } v; v.f = f;
    u32 u = v.u;
    u32 r = (u + 0x7FFFu + ((u >> 16) & 1u)) >> 16;   // RTNE
    return (u16)r;
}

// async 16B global->LDS (m97 pattern); dst must be lane-contiguous per wave
__device__ __forceinline__ void gload16(const void* g, void* l) {
    __builtin_amdgcn_global_load_lds(
        (const __attribute__((address_space(1))) void*)g,
        (__attribute__((address_space(3))) void*)l, 16, 0, 0);
}

// ---------------- six D_xD_ weight transposes in one launch ----------------
__global__ void transpose6(const float* s0, const float* s1, const float* s2,
                           const float* s3, const float* s4, const float* s5,
                           u16* d0, u16* d1, u16* d2, u16* d3, u16* d4, u16* d5)
{
    __shared__ u16 tile[32][33];
    int z = blockIdx.z;
    const float* W = (z == 0) ? s0 : (z == 1) ? s1 : (z == 2) ? s2
                   : (z == 3) ? s3 : (z == 4) ? s4 : s5;
    u16* WT = (z == 0) ? d0 : (z == 1) ? d1 : (z == 2) ? d2
            : (z == 3) ? d3 : (z == 4) ? d4 : d5;
    int c0 = blockIdx.x * 32, r0 = blockIdx.y * 32;
    int tx = threadIdx.x, ty = threadIdx.y;   // (32,8)
    #pragma unroll
    for (int j = 0; j < 32; j += 8)
        tile[ty + j][tx] = f2b(W[(size_t)(r0 + ty + j) * D_ + (c0 + tx)]);
    __syncthreads();
    #pragma unroll
    for (int j = 0; j < 32; j += 8)
        WT[(size_t)(c0 + ty + j) * D_ + (r0 + tx)] = tile[tx][ty + j];
}

// ---------------- generic transpose+cast: W[R,C] f32 -> WT[C,R] bf16 -------
__global__ void transpose_cast(const float* __restrict__ W, u16* __restrict__ WT,
                               int R, int C) {
    __shared__ u16 tile[32][33];
    int c0 = blockIdx.x * 32;
    int r0 = blockIdx.y * 32;
    int tx = threadIdx.x, ty = threadIdx.y;   // (32,8)
    #pragma unroll
    for (int j = 0; j < 32; j += 8)
        tile[ty + j][tx] = f2b(W[(size_t)(r0 + ty + j) * C + (c0 + tx)]);
    __syncthreads();
    #pragma unroll
    for (int j = 0; j < 32; j += 8)
        WT[(size_t)(c0 + ty + j) * R + (r0 + tx)] = tile[tx][ty + j];
}

// ---------------- bias concat ----------------
__global__ void bias_concat(const float* bqn, const float* bkn, const float* bq,
                            const float* bk, const float* bv,
                            float* bias_nk, float* bias_qkv)
{
    int i = blockIdx.x * 256 + threadIdx.x;    // 0..3839
    if (i < 768)       bias_nk[i] = bqn[i];
    else if (i < 1536) bias_nk[i] = bkn[i - 768];
    else if (i < 2304) bias_qkv[i - 1536] = bq[i - 1536];
    else if (i < 3072) bias_qkv[i - 1536] = bk[i - 2304];
    else if (i < 3840) bias_qkv[i - 1536] = bv[i - 3072];
}

// ---------------- MFMA GEMM, BK=64, global_load_lds, XOR-swizzled LDS ------
__launch_bounds__(256)
__global__ void gemm_mfma(const u16* __restrict__ A, const u16* __restrict__ BT,
                          const float* __restrict__ bias, const float* __restrict__ res,
                          u16* __restrict__ Cb, float* __restrict__ Cf,
                          int N, int K, int klen, int relu, int split)
{
    __shared__ __align__(16) u16 As[128 * 64];
    __shared__ __align__(16) u16 Bs[128 * 64];
    int tid = threadIdx.x;
    int wave = tid >> 6, lane = tid & 63;
    int m0 = blockIdx.y * 128, n0 = blockIdx.x * 128;
    int kbeg = blockIdx.z * klen;
    int wm = (wave >> 1) * 64, wn = (wave & 1) * 64;
    int r16 = lane & 15, kq = lane >> 4;
    f32x4 acc[4][4] = {};
    for (int k0 = 0; k0 < klen; k0 += 64) {
        #pragma unroll
        for (int i = 0; i < 4; ++i) {
            int cid = i * 256 + tid;          // 1024 chunks of 8 elems
            int row = cid >> 3, phys = cid & 7, logc = phys ^ (row & 7);
            gload16(&A [(size_t)(m0 + row) * K + kbeg + k0 + logc * 8], &As[cid * 8]);
            gload16(&BT[(size_t)(n0 + row) * K + kbeg + k0 + logc * 8], &Bs[cid * 8]);
        }
        __syncthreads();
        #pragma unroll
        for (int ks = 0; ks < 2; ++ks) {
            bf16x8 af[4], bfr[4];
            #pragma unroll
            for (int i = 0; i < 4; ++i) {
                int row = wm + i * 16 + r16;
                af[i] = *(const bf16x8*)&As[row * 64 + (((ks * 4 + kq) ^ (row & 7)) * 8)];
            }
            #pragma unroll
            for (int j = 0; j < 4; ++j) {
                int row = wn + j * 16 + r16;
                bfr[j] = *(const bf16x8*)&Bs[row * 64 + (((ks * 4 + kq) ^ (row & 7)) * 8)];
            }
            #pragma unroll
            for (int i = 0; i < 4; ++i)
                #pragma unroll
                for (int j = 0; j < 4; ++j)
                    acc[i][j] = __builtin_amdgcn_mfma_f32_16x16x32_bf16(
                        af[i], bfr[j], acc[i][j], 0, 0, 0);
        }
        __syncthreads();
    }
    if (split) {
        float* Pf = Cf + (size_t)blockIdx.z * M_ * N;
        #pragma unroll
        for (int i = 0; i < 4; ++i) {
            int rg = m0 + wm + i * 16 + kq * 4;
            #pragma unroll
            for (int j = 0; j < 4; ++j) {
                int cg = n0 + wn + j * 16 + r16;
                #pragma unroll
                for (int r = 0; r < 4; ++r)
                    Pf[(size_t)(rg + r) * N + cg] = acc[i][j][r];
            }
        }
        return;
    }
    #pragma unroll
    for (int i = 0; i < 4; ++i) {
        int rg = m0 + wm + i * 16 + kq * 4;
        #pragma unroll
        for (int j = 0; j < 4; ++j) {
            int cg = n0 + wn + j * 16 + r16;
            float bc = bias[cg];
            #pragma unroll
            for (int r = 0; r < 4; ++r) {
                float v = acc[i][j][r] + bc;
                if (relu) v = fmaxf(v, 0.f);
                size_t off = (size_t)(rg + r) * N + cg;
                if (res) v += res[off];
                if (Cb) Cb[off] = f2b(v);
                if (Cf) Cf[off] = v;
            }
        }
    }
}

// ---------------- reduce: out = res + bias + sum parts (final, no LN) ------
__global__ void reduce_k(const float* __restrict__ parts, int KS,
                         const float* __restrict__ res, const float* __restrict__ bias,
                         float* __restrict__ out, int N, int n4)
{
    int i4 = blockIdx.x * 256 + threadIdx.x;
    if (i4 >= n4) return;
    size_t base = (size_t)i4 * 4;
    int col = (int)(base % N);
    f32x4 acc = *(const f32x4*)(res + base);
    f32x4 bv = *(const f32x4*)(bias + col);
    acc.x += bv.x; acc.y += bv.y; acc.z += bv.z; acc.w += bv.w;
    const size_t MN = (size_t)M_ * N;
    for (int s = 0; s < KS; ++s) {
        f32x4 p = *(const f32x4*)(parts + s * MN + base);
        acc.x += p.x; acc.y += p.y; acc.z += p.z; acc.w += p.w;
    }
    *(f32x4*)(out + base) = acc;
}

// ---------------- reduce + LayerNorm fused (x1 path) ----------------
__global__ void reduce_ln_k(const float* __restrict__ parts, int KS,
                            const float* __restrict__ res, const float* __restrict__ bias,
                            const float* __restrict__ g, const float* __restrict__ be,
                            float* __restrict__ Xout, u16* __restrict__ Y)
{
    int row  = blockIdx.x * 4 + (threadIdx.x >> 6);
    int lane = threadIdx.x & 63;
    size_t rb = (size_t)row * D_;
    f32x4 xv[3];
    float s = 0.f, sq = 0.f;
    #pragma unroll
    for (int t = 0; t < 3; ++t) {
        int d = lane * 4 + t * 256;
        f32x4 a  = *(const f32x4*)(res + rb + d);
        f32x4 bv = *(const f32x4*)(bias + d);
        a.x += bv.x; a.y += bv.y; a.z += bv.z; a.w += bv.w;
        for (int ss = 0; ss < KS; ++ss) {
            f32x4 p = *(const f32x4*)(parts + (size_t)ss * M_ * D_ + rb + d);
            a.x += p.x; a.y += p.y; a.z += p.z; a.w += p.w;
        }
        *(f32x4*)(Xout + rb + d) = a;
        xv[t] = a;
        #pragma unroll
        for (int e = 0; e < 4; ++e) { float v = a[e]; s += v; sq += v * v; }
    }
    #pragma unroll
    for (int off = 32; off > 0; off >>= 1) {
        s  += __shfl_xor(s, off);
        sq += __shfl_xor(sq, off);
    }
    float m  = s * (1.f / (float)D_);
    float var = sq * (1.f / (float)D_) - m * m;
    float rs = rsqrtf(var + 1e-5f);
    u16* yr = Y + rb;
    #pragma unroll
    for (int t = 0; t < 3; ++t) {
        int d = lane * 4 + t * 256;
        f32x4 gv = *(const f32x4*)(g + d);
        f32x4 bv = *(const f32x4*)(be + d);
        u16x4 o;
        #pragma unroll
        for (int e = 0; e < 4; ++e)
            o[e] = f2b((xv[t][e] - m) * rs * gv[e] + bv[e]);
        *(u16x4*)(yr + d) = o;
    }
}

// ---------------- LayerNorm + optional raw cast output (reads x once) ------
__global__ void ln_cast_k(const float* __restrict__ X, const float* __restrict__ g,
                          const float* __restrict__ be, u16* __restrict__ Y,
                          u16* __restrict__ Ycast)
{
    int row  = blockIdx.x * 4 + (threadIdx.x >> 6);
    int lane = threadIdx.x & 63;
    const float* xr = X + (size_t)row * D_;
    f32x4 xv[3];
    float s = 0.f, sq = 0.f;
    #pragma unroll
    for (int t = 0; t < 3; ++t) {
        xv[t] = *(const f32x4*)(xr + lane * 4 + t * 256);
        #pragma unroll
        for (int e = 0; e < 4; ++e) { float v = xv[t][e]; s += v; sq += v * v; }
    }
    if (Ycast) {
        u16* yc = Ycast + (size_t)row * D_;
        #pragma unroll
        for (int t = 0; t < 3; ++t) {
            u16x4 o;
            #pragma unroll
            for (int e = 0; e < 4; ++e) o[e] = f2b(xv[t][e]);
            *(u16x4*)(yc + lane * 4 + t * 256) = o;
        }
    }
    #pragma unroll
    for (int off = 32; off > 0; off >>= 1) {
        s  += __shfl_xor(s, off);
        sq += __shfl_xor(sq, off);
    }
    float m  = s * (1.f / (float)D_);
    float var = sq * (1.f / (float)D_) - m * m;
    float rs = rsqrtf(var + 1e-5f);
    u16* yr = Y + (size_t)row * D_;
    #pragma unroll
    for (int t = 0; t < 3; ++t) {
        int d = lane * 4 + t * 256;
        f32x4 gv = *(const f32x4*)(g + d);
        f32x4 bv = *(const f32x4*)(be + d);
        u16x4 o;
        #pragma unroll
        for (int e = 0; e < 4; ++e)
            o[e] = f2b((xv[t][e] - m) * rs * gv[e] + bv[e]);
        *(u16x4*)(yr + d) = o;
    }
}

// ---------------- affinity: a[b,i] from fused nk buffer (stride 1536) -------
__global__ void affinity_k(const u16* __restrict__ nk,
                           const float* __restrict__ prev, const int* __restrict__ lidx,
                           float* __restrict__ a_out)
{
    const int ST = 2 * D_;
    int gid  = blockIdx.x * 4 + (threadIdx.x >> 6);
    int lane = threadIdx.x & 63;
    if (gid >= B_ * (S_ - 1)) return;
    int b = gid / (S_ - 1), i = gid % (S_ - 1);
    const u16* q0 = nk + (size_t)(b * S_ + i)     * ST;
    const u16* q1 = nk + (size_t)(b * S_ + i + 1) * ST;
    const u16* k0 = q0 + D_;
    const u16* k1 = q1 + D_;
    float sf = 0.f, sb = 0.f;
    for (int d = lane; d < D_; d += 64) {
        sf += b2f(q0[d]) * b2f(k1[d]);
        sb += b2f(q1[d]) * b2f(k0[d]);
    }
    #pragma unroll
    for (int off = 32; off > 0; off >>= 1) {
        sf += __shfl_xor(sf, off);
        sb += __shfl_xor(sb, off);
    }
    if (lane == 0) {
        sf *= (1.f / 64.f); sb *= (1.f / 64.f);
        float ah = 0.5f * (1.f / (1.f + expf(-sf)) + 1.f / (1.f + expf(-sb)));
        float a = ah;
        if (lidx[0] != 0) { float p = prev[gid]; a = p + (1.f - p) * ah; }
        a_out[gid] = a;
    }
}

// ---------------- L[b,k] = sum_{t<k} log a[b,t] ----------------
__global__ void cumsum_k(const float* __restrict__ a_f, float* __restrict__ L) {
    int b = blockIdx.x;
    int lane = threadIdx.x;
    float lg[8]; float s = 0.f;
    #pragma unroll
    for (int r = 0; r < 8; ++r) {
        int t = lane * 8 + r;
        lg[r] = (t < S_ - 1) ? logf(fmaxf(a_f[b * (S_ - 1) + t], 1e-35f)) : 0.f;
        s += lg[r];
    }
    float incl = s;
    #pragma unroll
    for (int off = 1; off < 64; off <<= 1) {
        float n = __shfl_up(incl, off);
        if (lane >= off) incl += n;
    }
    float run = incl - s;
    #pragma unroll
    for (int r = 0; r < 8; ++r) {
        L[b * S_ + lane * 8 + r] = run;
        run += lg[r];
    }
}

// ---------------- V^T per head: qkv V slice -> Vt[bh*64+d][512] bf16 --------
__global__ void vt_transpose(const u16* __restrict__ QKV, u16* __restrict__ Vt) {
    const int ST = 3 * D_;
    __shared__ u16 tile[32][33];
    int bh = blockIdx.z; int b = bh / H_, h = bh % H_;
    int j0 = blockIdx.x * 32;
    int d0 = blockIdx.y * 32;
    int tx = threadIdx.x, ty = threadIdx.y;   // (32,8)
    #pragma unroll
    for (int jj = 0; jj < 32; jj += 8)
        tile[ty + jj][tx] = QKV[(size_t)(b * S_ + j0 + ty + jj) * ST + 2 * D_ + h * DH_ + d0 + tx];
    __syncthreads();
    #pragma unroll
    for (int jj = 0; jj < 32; jj += 8)
        Vt[((size_t)bh * DH_ + d0 + ty + jj) * S_ + (j0 + tx)] = tile[tx][ty + jj];
}

// ---------------- fused attention: QK^T -> softmax -> C-mask -> PV ----------
// Swapped MFMA (A=K rows, B=Q rows): lane(r16,kq) reg r holds
// S[q = q0+wave*16+r16][j = jt*16+kq*4+r]  -> softmax is lane-local over j.
// v2: K/Q/V fragments read DIRECT from global (L2-resident; no LDS staging,
// no inter-phase barriers) -> 10 KB LDS, 3 blocks/CU, waves independent.
__launch_bounds__(256, 3)
__global__ void attn_fused(const u16* __restrict__ QKV, const u16* __restrict__ Vt,
                           const float* __restrict__ L,
                           float* __restrict__ Attn, u16* __restrict__ ctx)
{
    const int ST = 3 * D_;
    __shared__ __align__(16) u16 Pt_all[4 * 16 * 64];   // 8 KB (per-wave P tiles)
    __shared__ float Lsh[S_];                            // 2 KB
    int bh = blockIdx.y; int b = bh / H_, h = bh % H_;
    int q0 = blockIdx.x * 64;
    int tid = threadIdx.x;
    int wave = tid >> 6, lane = tid & 63;
    int r16 = lane & 15, kq = lane >> 4;

    for (int j = tid; j < S_; j += 256) Lsh[j] = L[b * S_ + j];

    // Q fragments direct from global (B-operand of swapped MFMA)
    int arow = wave * 16 + r16;
    const u16* qp = &QKV[(size_t)(b * S_ + q0 + arow) * ST + h * DH_];
    bf16x8 a0 = *(const bf16x8*)(qp + kq * 8);
    bf16x8 a1 = *(const bf16x8*)(qp + 32 + kq * 8);

    // QK^T: K fragments direct from global (A-operand rows)
    const u16* kbase = &QKV[(size_t)(b * S_) * ST + D_ + h * DH_];
    f32x4 acc[32];
    #pragma unroll
    for (int jt = 0; jt < 32; ++jt) {
        const u16* kp = kbase + (size_t)(jt * 16 + r16) * ST;
        bf16x8 b0 = *(const bf16x8*)(kp + kq * 8);
        bf16x8 b1 = *(const bf16x8*)(kp + 32 + kq * 8);
        f32x4 z = {0.f, 0.f, 0.f, 0.f};
        z = __builtin_amdgcn_mfma_f32_16x16x32_bf16(b0, a0, z, 0, 0, 0);   // swapped
        acc[jt] = __builtin_amdgcn_mfma_f32_16x16x32_bf16(b1, a1, z, 0, 0, 0);
    }

    // softmax stats: per-lane over 128 j + reduce across kq lanes (bits 4,5)
    float mx = -1e30f;
    #pragma unroll
    for (int jt = 0; jt < 32; ++jt)
        #pragma unroll
        for (int r = 0; r < 4; ++r)
            mx = fmaxf(mx, acc[jt][r] * 0.125f);
    mx = fmaxf(mx, __shfl_xor(mx, 16));
    mx = fmaxf(mx, __shfl_xor(mx, 32));
    float sum = 0.f;
    #pragma unroll
    for (int jt = 0; jt < 32; ++jt)
        #pragma unroll
        for (int r = 0; r < 4; ++r) {
            float e = __expf(acc[jt][r] * 0.125f - mx);
            acc[jt][r] = e; sum += e;
        }
    sum += __shfl_xor(sum, 16);
    sum += __shfl_xor(sum, 32);
    float inv = 1.f / sum;
    int qg = q0 + wave * 16 + r16;
    __syncthreads();              // Lsh ready (only barrier in kernel)
    float Lq = Lsh[qg];

    // pass 3: per 64-j chunk: normalize+C-mask, write Attn (f32x4), pack P
    // into per-wave swizzled LDS tile, PV MFMA with V^T direct from global.
    u16* Pt = &Pt_all[wave * 1024];
    const u16* vtb = Vt + (size_t)bh * DH_ * S_;
    size_t obase = (size_t)bh * S_ * S_ + (size_t)qg * S_;
    f32x4 accpv[4] = {};
    #pragma unroll
    for (int c = 0; c < 8; ++c) {
        #pragma unroll
        for (int jt4 = 0; jt4 < 4; ++jt4) {
            int jt = c * 4 + jt4;
            int j0c = jt * 16 + kq * 4;
            f32x4 Ljv = *(const f32x4*)&Lsh[j0c];
            f32x4 pv;
            #pragma unroll
            for (int r = 0; r < 4; ++r) {
                int j = j0c + r;
                float dr = (j >= qg) ? (Ljv[r] - Lq) : (Lq - Ljv[r]);
                pv[r] = acc[jt][r] * inv * __expf(fminf(dr, 0.f));
            }
            *(f32x4*)&Attn[obase + j0c] = pv;
            u32 lo = (u32)f2b(pv[0]) | ((u32)f2b(pv[1]) << 16);
            u32 hi = (u32)f2b(pv[2]) | ((u32)f2b(pv[3]) << 16);
            int jloc = jt4 * 16 + kq * 4;
            u32x2 pk; pk.x = lo; pk.y = hi;
            *(u32x2*)&Pt[r16 * 64 + (jloc ^ ((r16 & 7) << 3))] = pk;
        }
        #pragma unroll
        for (int ks = 0; ks < 2; ++ks) {
            bf16x8 ap = *(const bf16x8*)&Pt[r16 * 64 + ((ks * 32 + kq * 8) ^ ((r16 & 7) << 3))];
            #pragma unroll
            for (int n = 0; n < 4; ++n) {
                int d = n * 16 + r16;
                bf16x8 bv = *(const bf16x8*)&vtb[(size_t)d * S_ + c * 64 + ks * 32 + kq * 8];
                accpv[n] = __builtin_amdgcn_mfma_f32_16x16x32_bf16(ap, bv, accpv[n], 0, 0, 0);
            }
        }
    }
    // epilogue: ctx[q][d], q = q0+wave*16+kq*4+r, d = n*16+r16
    int qq = q0 + wave * 16 + kq * 4;
    #pragma unroll
    for (int n = 0; n < 4; ++n) {
        int d = n * 16 + r16;
        #pragma unroll
        for (int r = 0; r < 4; ++r)
            ctx[(size_t)(b * S_ + qq + r) * D_ + h * DH_ + d] = f2b(accpv[n][r]);
    }
}

// ---------------- launcher ----------------
extern "C" void kernel_launch(void* const* d_in, const int* in_sizes, int n_in,
                              void* d_out, int out_size, void* d_ws, size_t ws_size,
                              hipStream_t stream) {
    const float* x    = (const float*)d_in[0];
    const float* prev = (const float*)d_in[2];
    const float* Wqn = (const float*)d_in[3];  const float* bqn = (const float*)d_in[4];
    const float* Wkn = (const float*)d_in[5];  const float* bkn = (const float*)d_in[6];
    const float* Wq  = (const float*)d_in[7];  const float* bq  = (const float*)d_in[8];
    const float* Wk  = (const float*)d_in[9];  const float* bk  = (const float*)d_in[10];
    const float* Wv  = (const float*)d_in[11]; const float* bv  = (const float*)d_in[12];
    const float* Wo  = (const float*)d_in[13]; const float* bo  = (const float*)d_in[14];
    const float* W1  = (const float*)d_in[15]; const float* b1  = (const float*)d_in[16];
    const float* W2  = (const float*)d_in[17]; const float* b2  = (const float*)d_in[18];
    const float* g1  = (const float*)d_in[19]; const float* be1 = (const float*)d_in[20];
    const float* g2  = (const float*)d_in[21]; const float* be2 = (const float*)d_in[22];
    const int* lidx = (const int*)d_in[23];

    char* ws = (char*)d_ws;
    size_t off = 0;
    auto alloc = [&](size_t bytes) -> void* {
        void* p = ws + off; off += (bytes + 255) & ~(size_t)255; return p;
    };
    const size_t DDe = (size_t)D_ * D_;
    u16* WT_nk  = (u16*)alloc(2 * DDe * 2);
    u16* WT_qkv = (u16*)alloc(3 * DDe * 2);
    u16* WT_o   = (u16*)alloc(DDe * 2);
    u16* W1T    = (u16*)alloc((size_t)FF_ * D_ * 2);
    u16* W2T    = (u16*)alloc((size_t)FF_ * D_ * 2);
    float* bias_nk  = (float*)alloc(2 * D_ * 4);
    float* bias_qkv = (float*)alloc(3 * D_ * 4);
    u16* xb    = (u16*)alloc((size_t)M_ * D_ * 2);       // reused as Vt
    u16* nk_b  = (u16*)alloc((size_t)M_ * 2 * D_ * 2);
    u16* qkv_b = (u16*)alloc((size_t)M_ * 3 * D_ * 2);
    float* L_f = (float*)alloc((size_t)B_ * S_ * 4);
    u16* xn_b  = (u16*)alloc((size_t)M_ * D_ * 2);       // reused as xn2_b
    u16* ctx_b = (u16*)alloc((size_t)M_ * D_ * 2);
    float* x1_f = (float*)alloc((size_t)M_ * D_ * 4);
    float* parts = (float*)alloc((size_t)4 * M_ * D_ * 4);  // split-K partials
    u16* h_b = nk_b;      // FFN hidden aliases nk_b..qkv_b (dead by then)
    u16* xn2_b = xn_b;
    u16* Vt = xb;         // xb dead after nk gemm

    float* out0     = (float*)d_out;                       // [B,S,D]
    float* out_a    = out0 + (size_t)M_ * D_;              // [B,S-1]
    float* out_attn = out_a + (size_t)B_ * (S_ - 1);       // [B,H,S,S]

    dim3 tb(32, 8);
    // LN1 + raw cast of x in one pass
    ln_cast_k<<<M_ / 4, 256, 0, stream>>>(x, g1, be1, xn_b, xb);
    transpose6<<<dim3(D_/32, D_/32, 6), tb, 0, stream>>>(
        Wqn, Wkn, Wq, Wk, Wv, Wo,
        WT_nk, WT_nk + DDe, WT_qkv, WT_qkv + DDe, WT_qkv + 2 * DDe, WT_o);
    transpose_cast<<<dim3(FF_/32, D_/32), tb, 0, stream>>>(W1, W1T, D_, FF_);
    transpose_cast<<<dim3(D_/32, FF_/32), tb, 0, stream>>>(W2, W2T, FF_, D_);
    bias_concat<<<15, 256, 0, stream>>>(bqn, bkn, bq, bk, bv, bias_nk, bias_qkv);

    // nk = x @ [Wqn|Wkn]  (full-K)
    gemm_mfma<<<dim3(2*D_/128, M_/128), 256, 0, stream>>>(
        xb, WT_nk, bias_nk, nullptr, nk_b, nullptr, 2*D_, D_, D_, 0, 0);
    affinity_k<<<(B_ * (S_ - 1) + 3) / 4, 256, 0, stream>>>(nk_b, prev, lidx, out_a);
    cumsum_k<<<B_, 64, 0, stream>>>(out_a, L_f);

    // qkv = xn @ [Wq|Wk|Wv]  (full-K)
    gemm_mfma<<<dim3(3*D_/128, M_/128), 256, 0, stream>>>(
        xn_b, WT_qkv, bias_qkv, nullptr, qkv_b, nullptr, 3*D_, D_, D_, 0, 0);

    vt_transpose<<<dim3(S_/32, DH_/32, B_*H_), tb, 0, stream>>>(qkv_b, Vt);
    attn_fused<<<dim3(S_/64, B_*H_), 256, 0, stream>>>(qkv_b, Vt, L_f, out_attn, ctx_b);

    // x1 = x + bo + ctx@Wo  (split-K=2) then LN2, fused reduce+LN
    gemm_mfma<<<dim3(D_/128, M_/128, 2), 256, 0, stream>>>(
        ctx_b, WT_o, nullptr, nullptr, nullptr, parts, D_, D_, D_/2, 0, 1);
    reduce_ln_k<<<M_ / 4, 256, 0, stream>>>(parts, 2, x, bo, g2, be2, x1_f, xn2_b);
    // h = relu(xn2 @ W1 + b1)  (full-K)
    gemm_mfma<<<dim3(FF_/128, M_/128), 256, 0, stream>>>(
        xn2_b, W1T, b1, nullptr, h_b, nullptr, FF_, D_, D_, 1, 0);
    // out = x1 + b2 + h@W2  (split-K=4)
    gemm_mfma<<<dim3(D_/128, M_/128, 4), 256, 0, stream>>>(
        h_b, W2T, nullptr, nullptr, nullptr, parts, D_, FF_, FF_/4, 0, 1);
    reduce_k<<<(M_ * D_ / 4 + 255) / 256, 256, 0, stream>>>(
        parts, 4, x1_f, b2, out0, D_, M_ * D_ / 4);
}

// Round 6
// 450.610 us; speedup vs baseline: 1.0349x; 1.0349x over previous
//
#include <hip/hip_runtime.h>
#include <math.h>

// HierarchicalAttentionEncoderLayer — inputs f32, outputs f32, internals bf16.
// R6: attn v2 verified correct (R5). This round: V-transpose folded into qkv
// GEMM epilogue (drop vt_transpose), single transpose_all launch, FFN2 split-K 2.
#define B_  8
#define S_  512
#define D_  768
#define H_  12
#define DH_ 64
#define FF_ 3072
#define M_  (B_ * S_)   // 4096 rows

typedef unsigned short u16;
typedef unsigned int   u32;
typedef __bf16  bf16x8 __attribute__((ext_vector_type(8)));
typedef float   f32x4  __attribute__((ext_vector_type(4)));
typedef unsigned short u16x4 __attribute__((ext_vector_type(4)));
typedef unsigned int   u32x2 __attribute__((ext_vector_type(2)));

__device__ __forceinline__ float b2f(u16 h) {
    union { u32 u; float f; } v; v.u = ((u32)h) << 16; return v.f;
}
__device__ __forceinline__ u16 f2b(float f) {
    union { u32 u; float f; } v; v.f = f;
    u32 u = v.u;
    u32 r = (u + 0x7FFFu + ((u >> 16) & 1u)) >> 16;   // RTNE
    return (u16)r;
}

// async 16B global->LDS (m97 pattern); dst must be lane-contiguous per wave
__device__ __forceinline__ void gload16(const void* g, void* l) {
    __builtin_amdgcn_global_load_lds(
        (const __attribute__((address_space(1))) void*)g,
        (__attribute__((address_space(3))) void*)l, 16, 0, 0);
}

// ---------------- ALL weight transposes in one launch ----------------
// tiles: 6 x (768x768) = 3456, W1 (768x3072 -> 96x24) = 2304, W2 (3072x768) = 2304
__global__ void transpose_all(const float* Wqn, const float* Wkn, const float* Wq,
                              const float* Wk, const float* Wv, const float* Wo,
                              const float* W1, const float* W2,
                              u16* WT_nk, u16* WT_qkv, u16* WT_o,
                              u16* W1T, u16* W2T)
{
    __shared__ u16 tile[32][33];
    int t = blockIdx.x;
    const float* W; u16* WT; int R, C, bx, by;
    if (t < 3456) {
        int z = t / 576, rem = t % 576;
        bx = rem % 24; by = rem / 24; R = D_; C = D_;
        W  = (z == 0) ? Wqn : (z == 1) ? Wkn : (z == 2) ? Wq
           : (z == 3) ? Wk  : (z == 4) ? Wv  : Wo;
        const size_t DDe = (size_t)D_ * D_;
        WT = (z == 0) ? WT_nk : (z == 1) ? WT_nk + DDe : (z == 2) ? WT_qkv
           : (z == 3) ? WT_qkv + DDe : (z == 4) ? WT_qkv + 2 * DDe : WT_o;
    } else if (t < 5760) {
        int rem = t - 3456;
        bx = rem % 96; by = rem / 96; R = D_; C = FF_;
        W = W1; WT = W1T;
    } else {
        int rem = t - 5760;
        bx = rem % 24; by = rem / 24; R = FF_; C = D_;
        W = W2; WT = W2T;
    }
    int c0 = bx * 32, r0 = by * 32;
    int tx = threadIdx.x, ty = threadIdx.y;   // (32,8)
    #pragma unroll
    for (int j = 0; j < 32; j += 8)
        tile[ty + j][tx] = f2b(W[(size_t)(r0 + ty + j) * C + (c0 + tx)]);
    __syncthreads();
    #pragma unroll
    for (int j = 0; j < 32; j += 8)
        WT[(size_t)(c0 + ty + j) * R + (r0 + tx)] = tile[tx][ty + j];
}

// ---------------- bias concat ----------------
__global__ void bias_concat(const float* bqn, const float* bkn, const float* bq,
                            const float* bk, const float* bv,
                            float* bias_nk, float* bias_qkv)
{
    int i = blockIdx.x * 256 + threadIdx.x;    // 0..3839
    if (i < 768)       bias_nk[i] = bqn[i];
    else if (i < 1536) bias_nk[i] = bkn[i - 768];
    else if (i < 2304) bias_qkv[i - 1536] = bq[i - 1536];
    else if (i < 3072) bias_qkv[i - 1536] = bk[i - 2304];
    else if (i < 3840) bias_qkv[i - 1536] = bv[i - 3072];
}

// ---------------- MFMA GEMM, BK=64, global_load_lds, XOR-swizzled LDS ------
// split=0: C = A·BT + bias (+relu) -> Cb bf16 / Cf f32; if VtOut, columns
//          cg in [2D,3D) are written TRANSPOSED per head to VtOut instead.
// split=1: partial A·BT (k-slice blockIdx.z) streamed to Cf + z*M_*N (f32)
__launch_bounds__(256)
__global__ void gemm_mfma(const u16* __restrict__ A, const u16* __restrict__ BT,
                          const float* __restrict__ bias, const float* __restrict__ res,
                          u16* __restrict__ Cb, float* __restrict__ Cf,
                          u16* __restrict__ VtOut,
                          int N, int K, int klen, int relu, int split)
{
    __shared__ __align__(16) u16 As[128 * 64];
    __shared__ __align__(16) u16 Bs[128 * 64];
    int tid = threadIdx.x;
    int wave = tid >> 6, lane = tid & 63;
    int m0 = blockIdx.y * 128, n0 = blockIdx.x * 128;
    int kbeg = blockIdx.z * klen;
    int wm = (wave >> 1) * 64, wn = (wave & 1) * 64;
    int r16 = lane & 15, kq = lane >> 4;
    f32x4 acc[4][4] = {};
    for (int k0 = 0; k0 < klen; k0 += 64) {
        #pragma unroll
        for (int i = 0; i < 4; ++i) {
            int cid = i * 256 + tid;          // 1024 chunks of 8 elems
            int row = cid >> 3, phys = cid & 7, logc = phys ^ (row & 7);
            gload16(&A [(size_t)(m0 + row) * K + kbeg + k0 + logc * 8], &As[cid * 8]);
            gload16(&BT[(size_t)(n0 + row) * K + kbeg + k0 + logc * 8], &Bs[cid * 8]);
        }
        __syncthreads();
        #pragma unroll
        for (int ks = 0; ks < 2; ++ks) {
            bf16x8 af[4], bfr[4];
            #pragma unroll
            for (int i = 0; i < 4; ++i) {
                int row = wm + i * 16 + r16;
                af[i] = *(const bf16x8*)&As[row * 64 + (((ks * 4 + kq) ^ (row & 7)) * 8)];
            }
            #pragma unroll
            for (int j = 0; j < 4; ++j) {
                int row = wn + j * 16 + r16;
                bfr[j] = *(const bf16x8*)&Bs[row * 64 + (((ks * 4 + kq) ^ (row & 7)) * 8)];
            }
            #pragma unroll
            for (int i = 0; i < 4; ++i)
                #pragma unroll
                for (int j = 0; j < 4; ++j)
                    acc[i][j] = __builtin_amdgcn_mfma_f32_16x16x32_bf16(
                        af[i], bfr[j], acc[i][j], 0, 0, 0);
        }
        __syncthreads();
    }
    if (split) {
        float* Pf = Cf + (size_t)blockIdx.z * M_ * N;
        #pragma unroll
        for (int i = 0; i < 4; ++i) {
            int rg = m0 + wm + i * 16 + kq * 4;
            #pragma unroll
            for (int j = 0; j < 4; ++j) {
                int cg = n0 + wn + j * 16 + r16;
                #pragma unroll
                for (int r = 0; r < 4; ++r)
                    Pf[(size_t)(rg + r) * N + cg] = acc[i][j][r];
            }
        }
        return;
    }
    #pragma unroll
    for (int i = 0; i < 4; ++i) {
        int rg = m0 + wm + i * 16 + kq * 4;
        #pragma unroll
        for (int j = 0; j < 4; ++j) {
            int cg = n0 + wn + j * 16 + r16;
            float bc = bias[cg];
            if (VtOut && cg >= 2 * D_) {
                // V column: write transposed, Vt[(bh*64+d)*512 + s]
                int hd = cg - 2 * D_;                      // 0..767
                int bh = (rg >> 9) * H_ + (hd >> 6);
                int d  = hd & 63;
                u16* vp = VtOut + ((size_t)bh * DH_ + d) * S_ + (rg & 511);
                #pragma unroll
                for (int r = 0; r < 4; ++r)
                    vp[r] = f2b(acc[i][j][r] + bc);
            } else {
                #pragma unroll
                for (int r = 0; r < 4; ++r) {
                    float v = acc[i][j][r] + bc;
                    if (relu) v = fmaxf(v, 0.f);
                    size_t off = (size_t)(rg + r) * N + cg;
                    if (Cb) Cb[off] = f2b(v);
                    if (Cf) Cf[off] = v;
                }
            }
        }
    }
}

// ---------------- reduce: out = res + bias + sum parts (final, no LN) ------
__global__ void reduce_k(const float* __restrict__ parts, int KS,
                         const float* __restrict__ res, const float* __restrict__ bias,
                         float* __restrict__ out, int N, int n4)
{
    int i4 = blockIdx.x * 256 + threadIdx.x;
    if (i4 >= n4) return;
    size_t base = (size_t)i4 * 4;
    int col = (int)(base % N);
    f32x4 acc = *(const f32x4*)(res + base);
    f32x4 bv = *(const f32x4*)(bias + col);
    acc.x += bv.x; acc.y += bv.y; acc.z += bv.z; acc.w += bv.w;
    const size_t MN = (size_t)M_ * N;
    for (int s = 0; s < KS; ++s) {
        f32x4 p = *(const f32x4*)(parts + s * MN + base);
        acc.x += p.x; acc.y += p.y; acc.z += p.z; acc.w += p.w;
    }
    *(f32x4*)(out + base) = acc;
}

// ---------------- reduce + LayerNorm fused (x1 path) ----------------
__global__ void reduce_ln_k(const float* __restrict__ parts, int KS,
                            const float* __restrict__ res, const float* __restrict__ bias,
                            const float* __restrict__ g, const float* __restrict__ be,
                            float* __restrict__ Xout, u16* __restrict__ Y)
{
    int row  = blockIdx.x * 4 + (threadIdx.x >> 6);
    int lane = threadIdx.x & 63;
    size_t rb = (size_t)row * D_;
    f32x4 xv[3];
    float s = 0.f, sq = 0.f;
    #pragma unroll
    for (int t = 0; t < 3; ++t) {
        int d = lane * 4 + t * 256;
        f32x4 a  = *(const f32x4*)(res + rb + d);
        f32x4 bv = *(const f32x4*)(bias + d);
        a.x += bv.x; a.y += bv.y; a.z += bv.z; a.w += bv.w;
        for (int ss = 0; ss < KS; ++ss) {
            f32x4 p = *(const f32x4*)(parts + (size_t)ss * M_ * D_ + rb + d);
            a.x += p.x; a.y += p.y; a.z += p.z; a.w += p.w;
        }
        *(f32x4*)(Xout + rb + d) = a;
        xv[t] = a;
        #pragma unroll
        for (int e = 0; e < 4; ++e) { float v = a[e]; s += v; sq += v * v; }
    }
    #pragma unroll
    for (int off = 32; off > 0; off >>= 1) {
        s  += __shfl_xor(s, off);
        sq += __shfl_xor(sq, off);
    }
    float m  = s * (1.f / (float)D_);
    float var = sq * (1.f / (float)D_) - m * m;
    float rs = rsqrtf(var + 1e-5f);
    u16* yr = Y + rb;
    #pragma unroll
    for (int t = 0; t < 3; ++t) {
        int d = lane * 4 + t * 256;
        f32x4 gv = *(const f32x4*)(g + d);
        f32x4 bv = *(const f32x4*)(be + d);
        u16x4 o;
        #pragma unroll
        for (int e = 0; e < 4; ++e)
            o[e] = f2b((xv[t][e] - m) * rs * gv[e] + bv[e]);
        *(u16x4*)(yr + d) = o;
    }
}

// ---------------- LayerNorm + optional raw cast output (reads x once) ------
__global__ void ln_cast_k(const float* __restrict__ X, const float* __restrict__ g,
                          const float* __restrict__ be, u16* __restrict__ Y,
                          u16* __restrict__ Ycast)
{
    int row  = blockIdx.x * 4 + (threadIdx.x >> 6);
    int lane = threadIdx.x & 63;
    const float* xr = X + (size_t)row * D_;
    f32x4 xv[3];
    float s = 0.f, sq = 0.f;
    #pragma unroll
    for (int t = 0; t < 3; ++t) {
        xv[t] = *(const f32x4*)(xr + lane * 4 + t * 256);
        #pragma unroll
        for (int e = 0; e < 4; ++e) { float v = xv[t][e]; s += v; sq += v * v; }
    }
    if (Ycast) {
        u16* yc = Ycast + (size_t)row * D_;
        #pragma unroll
        for (int t = 0; t < 3; ++t) {
            u16x4 o;
            #pragma unroll
            for (int e = 0; e < 4; ++e) o[e] = f2b(xv[t][e]);
            *(u16x4*)(yc + lane * 4 + t * 256) = o;
        }
    }
    #pragma unroll
    for (int off = 32; off > 0; off >>= 1) {
        s  += __shfl_xor(s, off);
        sq += __shfl_xor(sq, off);
    }
    float m  = s * (1.f / (float)D_);
    float var = sq * (1.f / (float)D_) - m * m;
    float rs = rsqrtf(var + 1e-5f);
    u16* yr = Y + (size_t)row * D_;
    #pragma unroll
    for (int t = 0; t < 3; ++t) {
        int d = lane * 4 + t * 256;
        f32x4 gv = *(const f32x4*)(g + d);
        f32x4 bv = *(const f32x4*)(be + d);
        u16x4 o;
        #pragma unroll
        for (int e = 0; e < 4; ++e)
            o[e] = f2b((xv[t][e] - m) * rs * gv[e] + bv[e]);
        *(u16x4*)(yr + d) = o;
    }
}

// ---------------- affinity: a[b,i] from fused nk buffer (stride 1536) -------
__global__ void affinity_k(const u16* __restrict__ nk,
                           const float* __restrict__ prev, const int* __restrict__ lidx,
                           float* __restrict__ a_out)
{
    const int ST = 2 * D_;
    int gid  = blockIdx.x * 4 + (threadIdx.x >> 6);
    int lane = threadIdx.x & 63;
    if (gid >= B_ * (S_ - 1)) return;
    int b = gid / (S_ - 1), i = gid % (S_ - 1);
    const u16* q0 = nk + (size_t)(b * S_ + i)     * ST;
    const u16* q1 = nk + (size_t)(b * S_ + i + 1) * ST;
    const u16* k0 = q0 + D_;
    const u16* k1 = q1 + D_;
    float sf = 0.f, sb = 0.f;
    for (int d = lane; d < D_; d += 64) {
        sf += b2f(q0[d]) * b2f(k1[d]);
        sb += b2f(q1[d]) * b2f(k0[d]);
    }
    #pragma unroll
    for (int off = 32; off > 0; off >>= 1) {
        sf += __shfl_xor(sf, off);
        sb += __shfl_xor(sb, off);
    }
    if (lane == 0) {
        sf *= (1.f / 64.f); sb *= (1.f / 64.f);
        float ah = 0.5f * (1.f / (1.f + expf(-sf)) + 1.f / (1.f + expf(-sb)));
        float a = ah;
        if (lidx[0] != 0) { float p = prev[gid]; a = p + (1.f - p) * ah; }
        a_out[gid] = a;
    }
}

// ---------------- L[b,k] = sum_{t<k} log a[b,t] ----------------
__global__ void cumsum_k(const float* __restrict__ a_f, float* __restrict__ L) {
    int b = blockIdx.x;
    int lane = threadIdx.x;
    float lg[8]; float s = 0.f;
    #pragma unroll
    for (int r = 0; r < 8; ++r) {
        int t = lane * 8 + r;
        lg[r] = (t < S_ - 1) ? logf(fmaxf(a_f[b * (S_ - 1) + t], 1e-35f)) : 0.f;
        s += lg[r];
    }
    float incl = s;
    #pragma unroll
    for (int off = 1; off < 64; off <<= 1) {
        float n = __shfl_up(incl, off);
        if (lane >= off) incl += n;
    }
    float run = incl - s;
    #pragma unroll
    for (int r = 0; r < 8; ++r) {
        L[b * S_ + lane * 8 + r] = run;
        run += lg[r];
    }
}

// ---------------- fused attention: QK^T -> softmax -> C-mask -> PV ----------
// Swapped MFMA (A=K rows, B=Q rows): lane(r16,kq) reg r holds
// S[q = q0+wave*16+r16][j = jt*16+kq*4+r]  -> softmax is lane-local over j.
// v2: K/Q/V fragments read DIRECT from global (L2-resident; no LDS staging,
// no inter-phase barriers) -> 10 KB LDS, 3 blocks/CU, waves independent.
__launch_bounds__(256, 3)
__global__ void attn_fused(const u16* __restrict__ QKV, const u16* __restrict__ Vt,
                           const float* __restrict__ L,
                           float* __restrict__ Attn, u16* __restrict__ ctx)
{
    const int ST = 3 * D_;
    __shared__ __align__(16) u16 Pt_all[4 * 16 * 64];   // 8 KB (per-wave P tiles)
    __shared__ float Lsh[S_];                            // 2 KB
    int bh = blockIdx.y; int b = bh / H_, h = bh % H_;
    int q0 = blockIdx.x * 64;
    int tid = threadIdx.x;
    int wave = tid >> 6, lane = tid & 63;
    int r16 = lane & 15, kq = lane >> 4;

    for (int j = tid; j < S_; j += 256) Lsh[j] = L[b * S_ + j];

    // Q fragments direct from global (B-operand of swapped MFMA)
    int arow = wave * 16 + r16;
    const u16* qp = &QKV[(size_t)(b * S_ + q0 + arow) * ST + h * DH_];
    bf16x8 a0 = *(const bf16x8*)(qp + kq * 8);
    bf16x8 a1 = *(const bf16x8*)(qp + 32 + kq * 8);

    // QK^T: K fragments direct from global (A-operand rows)
    const u16* kbase = &QKV[(size_t)(b * S_) * ST + D_ + h * DH_];
    f32x4 acc[32];
    #pragma unroll
    for (int jt = 0; jt < 32; ++jt) {
        const u16* kp = kbase + (size_t)(jt * 16 + r16) * ST;
        bf16x8 b0 = *(const bf16x8*)(kp + kq * 8);
        bf16x8 b1 = *(const bf16x8*)(kp + 32 + kq * 8);
        f32x4 z = {0.f, 0.f, 0.f, 0.f};
        z = __builtin_amdgcn_mfma_f32_16x16x32_bf16(b0, a0, z, 0, 0, 0);   // swapped
        acc[jt] = __builtin_amdgcn_mfma_f32_16x16x32_bf16(b1, a1, z, 0, 0, 0);
    }

    // softmax stats: per-lane over 128 j + reduce across kq lanes (bits 4,5)
    float mx = -1e30f;
    #pragma unroll
    for (int jt = 0; jt < 32; ++jt)
        #pragma unroll
        for (int r = 0; r < 4; ++r)
            mx = fmaxf(mx, acc[jt][r] * 0.125f);
    mx = fmaxf(mx, __shfl_xor(mx, 16));
    mx = fmaxf(mx, __shfl_xor(mx, 32));
    float sum = 0.f;
    #pragma unroll
    for (int jt = 0; jt < 32; ++jt)
        #pragma unroll
        for (int r = 0; r < 4; ++r) {
            float e = __expf(acc[jt][r] * 0.125f - mx);
            acc[jt][r] = e; sum += e;
        }
    sum += __shfl_xor(sum, 16);
    sum += __shfl_xor(sum, 32);
    float inv = 1.f / sum;
    int qg = q0 + wave * 16 + r16;
    __syncthreads();              // Lsh ready (only barrier in kernel)
    float Lq = Lsh[qg];

    // pass 3: per 64-j chunk: normalize+C-mask, write Attn (f32x4), pack P
    // into per-wave swizzled LDS tile, PV MFMA with V^T direct from global.
    u16* Pt = &Pt_all[wave * 1024];
    const u16* vtb = Vt + (size_t)bh * DH_ * S_;
    size_t obase = (size_t)bh * S_ * S_ + (size_t)qg * S_;
    f32x4 accpv[4] = {};
    #pragma unroll
    for (int c = 0; c < 8; ++c) {
        #pragma unroll
        for (int jt4 = 0; jt4 < 4; ++jt4) {
            int jt = c * 4 + jt4;
            int j0c = jt * 16 + kq * 4;
            f32x4 Ljv = *(const f32x4*)&Lsh[j0c];
            f32x4 pv;
            #pragma unroll
            for (int r = 0; r < 4; ++r) {
                int j = j0c + r;
                float dr = (j >= qg) ? (Ljv[r] - Lq) : (Lq - Ljv[r]);
                pv[r] = acc[jt][r] * inv * __expf(fminf(dr, 0.f));
            }
            *(f32x4*)&Attn[obase + j0c] = pv;
            u32 lo = (u32)f2b(pv[0]) | ((u32)f2b(pv[1]) << 16);
            u32 hi = (u32)f2b(pv[2]) | ((u32)f2b(pv[3]) << 16);
            int jloc = jt4 * 16 + kq * 4;
            u32x2 pk; pk.x = lo; pk.y = hi;
            *(u32x2*)&Pt[r16 * 64 + (jloc ^ ((r16 & 7) << 3))] = pk;
        }
        #pragma unroll
        for (int ks = 0; ks < 2; ++ks) {
            bf16x8 ap = *(const bf16x8*)&Pt[r16 * 64 + ((ks * 32 + kq * 8) ^ ((r16 & 7) << 3))];
            #pragma unroll
            for (int n = 0; n < 4; ++n) {
                int d = n * 16 + r16;
                bf16x8 bv = *(const bf16x8*)&vtb[(size_t)d * S_ + c * 64 + ks * 32 + kq * 8];
                accpv[n] = __builtin_amdgcn_mfma_f32_16x16x32_bf16(ap, bv, accpv[n], 0, 0, 0);
            }
        }
    }
    // epilogue: ctx[q][d], q = q0+wave*16+kq*4+r, d = n*16+r16
    int qq = q0 + wave * 16 + kq * 4;
    #pragma unroll
    for (int n = 0; n < 4; ++n) {
        int d = n * 16 + r16;
        #pragma unroll
        for (int r = 0; r < 4; ++r)
            ctx[(size_t)(b * S_ + qq + r) * D_ + h * DH_ + d] = f2b(accpv[n][r]);
    }
}

// ---------------- launcher ----------------
extern "C" void kernel_launch(void* const* d_in, const int* in_sizes, int n_in,
                              void* d_out, int out_size, void* d_ws, size_t ws_size,
                              hipStream_t stream) {
    const float* x    = (const float*)d_in[0];
    const float* prev = (const float*)d_in[2];
    const float* Wqn = (const float*)d_in[3];  const float* bqn = (const float*)d_in[4];
    const float* Wkn = (const float*)d_in[5];  const float* bkn = (const float*)d_in[6];
    const float* Wq  = (const float*)d_in[7];  const float* bq  = (const float*)d_in[8];
    const float* Wk  = (const float*)d_in[9];  const float* bk  = (const float*)d_in[10];
    const float* Wv  = (const float*)d_in[11]; const float* bv  = (const float*)d_in[12];
    const float* Wo  = (const float*)d_in[13]; const float* bo  = (const float*)d_in[14];
    const float* W1  = (const float*)d_in[15]; const float* b1  = (const float*)d_in[16];
    const float* W2  = (const float*)d_in[17]; const float* b2  = (const float*)d_in[18];
    const float* g1  = (const float*)d_in[19]; const float* be1 = (const float*)d_in[20];
    const float* g2  = (const float*)d_in[21]; const float* be2 = (const float*)d_in[22];
    const int* lidx = (const int*)d_in[23];

    char* ws = (char*)d_ws;
    size_t off = 0;
    auto alloc = [&](size_t bytes) -> void* {
        void* p = ws + off; off += (bytes + 255) & ~(size_t)255; return p;
    };
    const size_t DDe = (size_t)D_ * D_;
    u16* WT_nk  = (u16*)alloc(2 * DDe * 2);
    u16* WT_qkv = (u16*)alloc(3 * DDe * 2);
    u16* WT_o   = (u16*)alloc(DDe * 2);
    u16* W1T    = (u16*)alloc((size_t)FF_ * D_ * 2);
    u16* W2T    = (u16*)alloc((size_t)FF_ * D_ * 2);
    float* bias_nk  = (float*)alloc(2 * D_ * 4);
    float* bias_qkv = (float*)alloc(3 * D_ * 4);
    u16* xb    = (u16*)alloc((size_t)M_ * D_ * 2);       // reused as Vt
    u16* nk_b  = (u16*)alloc((size_t)M_ * 2 * D_ * 2);
    u16* qkv_b = (u16*)alloc((size_t)M_ * 3 * D_ * 2);
    float* L_f = (float*)alloc((size_t)B_ * S_ * 4);
    u16* xn_b  = (u16*)alloc((size_t)M_ * D_ * 2);       // reused as xn2_b
    u16* ctx_b = (u16*)alloc((size_t)M_ * D_ * 2);
    float* x1_f = (float*)alloc((size_t)M_ * D_ * 4);
    float* parts = (float*)alloc((size_t)4 * M_ * D_ * 4);  // split-K partials
    u16* h_b = nk_b;      // FFN hidden aliases nk_b..qkv_b (dead by then)
    u16* xn2_b = xn_b;
    u16* Vt = xb;         // xb dead after nk gemm; qkv gemm writes V here

    float* out0     = (float*)d_out;                       // [B,S,D]
    float* out_a    = out0 + (size_t)M_ * D_;              // [B,S-1]
    float* out_attn = out_a + (size_t)B_ * (S_ - 1);       // [B,H,S,S]

    dim3 tb(32, 8);
    // LN1 + raw cast of x in one pass
    ln_cast_k<<<M_ / 4, 256, 0, stream>>>(x, g1, be1, xn_b, xb);
    transpose_all<<<8064, tb, 0, stream>>>(
        Wqn, Wkn, Wq, Wk, Wv, Wo, W1, W2,
        WT_nk, WT_qkv, WT_o, W1T, W2T);
    bias_concat<<<15, 256, 0, stream>>>(bqn, bkn, bq, bk, bv, bias_nk, bias_qkv);

    // nk = x @ [Wqn|Wkn]  (full-K)
    gemm_mfma<<<dim3(2*D_/128, M_/128), 256, 0, stream>>>(
        xb, WT_nk, bias_nk, nullptr, nk_b, nullptr, nullptr, 2*D_, D_, D_, 0, 0);
    affinity_k<<<(B_ * (S_ - 1) + 3) / 4, 256, 0, stream>>>(nk_b, prev, lidx, out_a);
    cumsum_k<<<B_, 64, 0, stream>>>(out_a, L_f);

    // qkv = xn @ [Wq|Wk|Wv]  (full-K); V columns written transposed to Vt
    gemm_mfma<<<dim3(3*D_/128, M_/128), 256, 0, stream>>>(
        xn_b, WT_qkv, bias_qkv, nullptr, qkv_b, nullptr, Vt, 3*D_, D_, D_, 0, 0);

    attn_fused<<<dim3(S_/64, B_*H_), 256, 0, stream>>>(qkv_b, Vt, L_f, out_attn, ctx_b);

    // x1 = x + bo + ctx@Wo  (split-K=2) then LN2, fused reduce+LN
    gemm_mfma<<<dim3(D_/128, M_/128, 2), 256, 0, stream>>>(
        ctx_b, WT_o, nullptr, nullptr, nullptr, parts, nullptr, D_, D_, D_/2, 0, 1);
    reduce_ln_k<<<M_ / 4, 256, 0, stream>>>(parts, 2, x, bo, g2, be2, x1_f, xn2_b);
    // h = relu(xn2 @ W1 + b1)  (full-K)
    gemm_mfma<<<dim3(FF_/128, M_/128), 256, 0, stream>>>(
        xn2_b, W1T, b1, nullptr, h_b, nullptr, nullptr, FF_, D_, D_, 1, 0);
    // out = x1 + b2 + h@W2  (split-K=2)
    gemm_mfma<<<dim3(D_/128, M_/128, 2), 256, 0, stream>>>(
        h_b, W2T, nullptr, nullptr, nullptr, parts, nullptr, D_, FF_, FF_/2, 0, 1);
    reduce_k<<<(M_ * D_ / 4 + 255) / 256, 256, 0, stream>>>(
        parts, 2, x1_f, b2, out0, D_, M_ * D_ / 4);
}

// Round 8
// 448.145 us; speedup vs baseline: 1.0406x; 1.0055x over previous
//
#include <hip/hip_runtime.h>
#include <math.h>

// HierarchicalAttentionEncoderLayer — inputs f32, outputs f32, internals bf16.
// R8 (= R7 resubmit; infra timeout, never measured):
// single change vs R6 — attn_fused launch bound (256,3) -> (256,2).
// R6 counters showed VGPR=84 (acc[32] spilled to scratch; +31 MB WRITE_SIZE,
// dur 77->107). Bound=2 gives 256-VGPR budget; no spill.
#define B_  8
#define S_  512
#define D_  768
#define H_  12
#define DH_ 64
#define FF_ 3072
#define M_  (B_ * S_)   // 4096 rows

typedef unsigned short u16;
typedef unsigned int   u32;
typedef __bf16  bf16x8 __attribute__((ext_vector_type(8)));
typedef float   f32x4  __attribute__((ext_vector_type(4)));
typedef unsigned short u16x4 __attribute__((ext_vector_type(4)));
typedef unsigned int   u32x2 __attribute__((ext_vector_type(2)));

__device__ __forceinline__ float b2f(u16 h) {
    union { u32 u; float f; } v; v.u = ((u32)h) << 16; return v.f;
}
__device__ __forceinline__ u16 f2b(float f) {
    union { u32 u; float f; } v; v.f = f;
    u32 u = v.u;
    u32 r = (u + 0x7FFFu + ((u >> 16) & 1u)) >> 16;   // RTNE
    return (u16)r;
}

// async 16B global->LDS (m97 pattern); dst must be lane-contiguous per wave
__device__ __forceinline__ void gload16(const void* g, void* l) {
    __builtin_amdgcn_global_load_lds(
        (const __attribute__((address_space(1))) void*)g,
        (__attribute__((address_space(3))) void*)l, 16, 0, 0);
}

// ---------------- ALL weight transposes in one launch ----------------
// tiles: 6 x (768x768) = 3456, W1 (768x3072 -> 96x24) = 2304, W2 (3072x768) = 2304
__global__ void transpose_all(const float* Wqn, const float* Wkn, const float* Wq,
                              const float* Wk, const float* Wv, const float* Wo,
                              const float* W1, const float* W2,
                              u16* WT_nk, u16* WT_qkv, u16* WT_o,
                              u16* W1T, u16* W2T)
{
    __shared__ u16 tile[32][33];
    int t = blockIdx.x;
    const float* W; u16* WT; int R, C, bx, by;
    if (t < 3456) {
        int z = t / 576, rem = t % 576;
        bx = rem % 24; by = rem / 24; R = D_; C = D_;
        W  = (z == 0) ? Wqn : (z == 1) ? Wkn : (z == 2) ? Wq
           : (z == 3) ? Wk  : (z == 4) ? Wv  : Wo;
        const size_t DDe = (size_t)D_ * D_;
        WT = (z == 0) ? WT_nk : (z == 1) ? WT_nk + DDe : (z == 2) ? WT_qkv
           : (z == 3) ? WT_qkv + DDe : (z == 4) ? WT_qkv + 2 * DDe : WT_o;
    } else if (t < 5760) {
        int rem = t - 3456;
        bx = rem % 96; by = rem / 96; R = D_; C = FF_;
        W = W1; WT = W1T;
    } else {
        int rem = t - 5760;
        bx = rem % 24; by = rem / 24; R = FF_; C = D_;
        W = W2; WT = W2T;
    }
    int c0 = bx * 32, r0 = by * 32;
    int tx = threadIdx.x, ty = threadIdx.y;   // (32,8)
    #pragma unroll
    for (int j = 0; j < 32; j += 8)
        tile[ty + j][tx] = f2b(W[(size_t)(r0 + ty + j) * C + (c0 + tx)]);
    __syncthreads();
    #pragma unroll
    for (int j = 0; j < 32; j += 8)
        WT[(size_t)(c0 + ty + j) * R + (r0 + tx)] = tile[tx][ty + j];
}

// ---------------- bias concat ----------------
__global__ void bias_concat(const float* bqn, const float* bkn, const float* bq,
                            const float* bk, const float* bv,
                            float* bias_nk, float* bias_qkv)
{
    int i = blockIdx.x * 256 + threadIdx.x;    // 0..3839
    if (i < 768)       bias_nk[i] = bqn[i];
    else if (i < 1536) bias_nk[i] = bkn[i - 768];
    else if (i < 2304) bias_qkv[i - 1536] = bq[i - 1536];
    else if (i < 3072) bias_qkv[i - 1536] = bk[i - 2304];
    else if (i < 3840) bias_qkv[i - 1536] = bv[i - 3072];
}

// ---------------- MFMA GEMM, BK=64, global_load_lds, XOR-swizzled LDS ------
// split=0: C = A·BT + bias (+relu) -> Cb bf16 / Cf f32; if VtOut, columns
//          cg in [2D,3D) are written TRANSPOSED per head to VtOut instead.
// split=1: partial A·BT (k-slice blockIdx.z) streamed to Cf + z*M_*N (f32)
__launch_bounds__(256)
__global__ void gemm_mfma(const u16* __restrict__ A, const u16* __restrict__ BT,
                          const float* __restrict__ bias, const float* __restrict__ res,
                          u16* __restrict__ Cb, float* __restrict__ Cf,
                          u16* __restrict__ VtOut,
                          int N, int K, int klen, int relu, int split)
{
    __shared__ __align__(16) u16 As[128 * 64];
    __shared__ __align__(16) u16 Bs[128 * 64];
    int tid = threadIdx.x;
    int wave = tid >> 6, lane = tid & 63;
    int m0 = blockIdx.y * 128, n0 = blockIdx.x * 128;
    int kbeg = blockIdx.z * klen;
    int wm = (wave >> 1) * 64, wn = (wave & 1) * 64;
    int r16 = lane & 15, kq = lane >> 4;
    f32x4 acc[4][4] = {};
    for (int k0 = 0; k0 < klen; k0 += 64) {
        #pragma unroll
        for (int i = 0; i < 4; ++i) {
            int cid = i * 256 + tid;          // 1024 chunks of 8 elems
            int row = cid >> 3, phys = cid & 7, logc = phys ^ (row & 7);
            gload16(&A [(size_t)(m0 + row) * K + kbeg + k0 + logc * 8], &As[cid * 8]);
            gload16(&BT[(size_t)(n0 + row) * K + kbeg + k0 + logc * 8], &Bs[cid * 8]);
        }
        __syncthreads();
        #pragma unroll
        for (int ks = 0; ks < 2; ++ks) {
            bf16x8 af[4], bfr[4];
            #pragma unroll
            for (int i = 0; i < 4; ++i) {
                int row = wm + i * 16 + r16;
                af[i] = *(const bf16x8*)&As[row * 64 + (((ks * 4 + kq) ^ (row & 7)) * 8)];
            }
            #pragma unroll
            for (int j = 0; j < 4; ++j) {
                int row = wn + j * 16 + r16;
                bfr[j] = *(const bf16x8*)&Bs[row * 64 + (((ks * 4 + kq) ^ (row & 7)) * 8)];
            }
            #pragma unroll
            for (int i = 0; i < 4; ++i)
                #pragma unroll
                for (int j = 0; j < 4; ++j)
                    acc[i][j] = __builtin_amdgcn_mfma_f32_16x16x32_bf16(
                        af[i], bfr[j], acc[i][j], 0, 0, 0);
        }
        __syncthreads();
    }
    if (split) {
        float* Pf = Cf + (size_t)blockIdx.z * M_ * N;
        #pragma unroll
        for (int i = 0; i < 4; ++i) {
            int rg = m0 + wm + i * 16 + kq * 4;
            #pragma unroll
            for (int j = 0; j < 4; ++j) {
                int cg = n0 + wn + j * 16 + r16;
                #pragma unroll
                for (int r = 0; r < 4; ++r)
                    Pf[(size_t)(rg + r) * N + cg] = acc[i][j][r];
            }
        }
        return;
    }
    #pragma unroll
    for (int i = 0; i < 4; ++i) {
        int rg = m0 + wm + i * 16 + kq * 4;
        #pragma unroll
        for (int j = 0; j < 4; ++j) {
            int cg = n0 + wn + j * 16 + r16;
            float bc = bias[cg];
            if (VtOut && cg >= 2 * D_) {
                // V column: write transposed, Vt[(bh*64+d)*512 + s]
                int hd = cg - 2 * D_;                      // 0..767
                int bh = (rg >> 9) * H_ + (hd >> 6);
                int d  = hd & 63;
                u16* vp = VtOut + ((size_t)bh * DH_ + d) * S_ + (rg & 511);
                #pragma unroll
                for (int r = 0; r < 4; ++r)
                    vp[r] = f2b(acc[i][j][r] + bc);
            } else {
                #pragma unroll
                for (int r = 0; r < 4; ++r) {
                    float v = acc[i][j][r] + bc;
                    if (relu) v = fmaxf(v, 0.f);
                    size_t off = (size_t)(rg + r) * N + cg;
                    if (Cb) Cb[off] = f2b(v);
                    if (Cf) Cf[off] = v;
                }
            }
        }
    }
}

// ---------------- reduce: out = res + bias + sum parts (final, no LN) ------
__global__ void reduce_k(const float* __restrict__ parts, int KS,
                         const float* __restrict__ res, const float* __restrict__ bias,
                         float* __restrict__ out, int N, int n4)
{
    int i4 = blockIdx.x * 256 + threadIdx.x;
    if (i4 >= n4) return;
    size_t base = (size_t)i4 * 4;
    int col = (int)(base % N);
    f32x4 acc = *(const f32x4*)(res + base);
    f32x4 bv = *(const f32x4*)(bias + col);
    acc.x += bv.x; acc.y += bv.y; acc.z += bv.z; acc.w += bv.w;
    const size_t MN = (size_t)M_ * N;
    for (int s = 0; s < KS; ++s) {
        f32x4 p = *(const f32x4*)(parts + s * MN + base);
        acc.x += p.x; acc.y += p.y; acc.z += p.z; acc.w += p.w;
    }
    *(f32x4*)(out + base) = acc;
}

// ---------------- reduce + LayerNorm fused (x1 path) ----------------
__global__ void reduce_ln_k(const float* __restrict__ parts, int KS,
                            const float* __restrict__ res, const float* __restrict__ bias,
                            const float* __restrict__ g, const float* __restrict__ be,
                            float* __restrict__ Xout, u16* __restrict__ Y)
{
    int row  = blockIdx.x * 4 + (threadIdx.x >> 6);
    int lane = threadIdx.x & 63;
    size_t rb = (size_t)row * D_;
    f32x4 xv[3];
    float s = 0.f, sq = 0.f;
    #pragma unroll
    for (int t = 0; t < 3; ++t) {
        int d = lane * 4 + t * 256;
        f32x4 a  = *(const f32x4*)(res + rb + d);
        f32x4 bv = *(const f32x4*)(bias + d);
        a.x += bv.x; a.y += bv.y; a.z += bv.z; a.w += bv.w;
        for (int ss = 0; ss < KS; ++ss) {
            f32x4 p = *(const f32x4*)(parts + (size_t)ss * M_ * D_ + rb + d);
            a.x += p.x; a.y += p.y; a.z += p.z; a.w += p.w;
        }
        *(f32x4*)(Xout + rb + d) = a;
        xv[t] = a;
        #pragma unroll
        for (int e = 0; e < 4; ++e) { float v = a[e]; s += v; sq += v * v; }
    }
    #pragma unroll
    for (int off = 32; off > 0; off >>= 1) {
        s  += __shfl_xor(s, off);
        sq += __shfl_xor(sq, off);
    }
    float m  = s * (1.f / (float)D_);
    float var = sq * (1.f / (float)D_) - m * m;
    float rs = rsqrtf(var + 1e-5f);
    u16* yr = Y + rb;
    #pragma unroll
    for (int t = 0; t < 3; ++t) {
        int d = lane * 4 + t * 256;
        f32x4 gv = *(const f32x4*)(g + d);
        f32x4 bv = *(const f32x4*)(be + d);
        u16x4 o;
        #pragma unroll
        for (int e = 0; e < 4; ++e)
            o[e] = f2b((xv[t][e] - m) * rs * gv[e] + bv[e]);
        *(u16x4*)(yr + d) = o;
    }
}

// ---------------- LayerNorm + optional raw cast output (reads x once) ------
__global__ void ln_cast_k(const float* __restrict__ X, const float* __restrict__ g,
                          const float* __restrict__ be, u16* __restrict__ Y,
                          u16* __restrict__ Ycast)
{
    int row  = blockIdx.x * 4 + (threadIdx.x >> 6);
    int lane = threadIdx.x & 63;
    const float* xr = X + (size_t)row * D_;
    f32x4 xv[3];
    float s = 0.f, sq = 0.f;
    #pragma unroll
    for (int t = 0; t < 3; ++t) {
        xv[t] = *(const f32x4*)(xr + lane * 4 + t * 256);
        #pragma unroll
        for (int e = 0; e < 4; ++e) { float v = xv[t][e]; s += v; sq += v * v; }
    }
    if (Ycast) {
        u16* yc = Ycast + (size_t)row * D_;
        #pragma unroll
        for (int t = 0; t < 3; ++t) {
            u16x4 o;
            #pragma unroll
            for (int e = 0; e < 4; ++e) o[e] = f2b(xv[t][e]);
            *(u16x4*)(yc + lane * 4 + t * 256) = o;
        }
    }
    #pragma unroll
    for (int off = 32; off > 0; off >>= 1) {
        s  += __shfl_xor(s, off);
        sq += __shfl_xor(sq, off);
    }
    float m  = s * (1.f / (float)D_);
    float var = sq * (1.f / (float)D_) - m * m;
    float rs = rsqrtf(var + 1e-5f);
    u16* yr = Y + (size_t)row * D_;
    #pragma unroll
    for (int t = 0; t < 3; ++t) {
        int d = lane * 4 + t * 256;
        f32x4 gv = *(const f32x4*)(g + d);
        f32x4 bv = *(const f32x4*)(be + d);
        u16x4 o;
        #pragma unroll
        for (int e = 0; e < 4; ++e)
            o[e] = f2b((xv[t][e] - m) * rs * gv[e] + bv[e]);
        *(u16x4*)(yr + d) = o;
    }
}

// ---------------- affinity: a[b,i] from fused nk buffer (stride 1536) -------
__global__ void affinity_k(const u16* __restrict__ nk,
                           const float* __restrict__ prev, const int* __restrict__ lidx,
                           float* __restrict__ a_out)
{
    const int ST = 2 * D_;
    int gid  = blockIdx.x * 4 + (threadIdx.x >> 6);
    int lane = threadIdx.x & 63;
    if (gid >= B_ * (S_ - 1)) return;
    int b = gid / (S_ - 1), i = gid % (S_ - 1);
    const u16* q0 = nk + (size_t)(b * S_ + i)     * ST;
    const u16* q1 = nk + (size_t)(b * S_ + i + 1) * ST;
    const u16* k0 = q0 + D_;
    const u16* k1 = q1 + D_;
    float sf = 0.f, sb = 0.f;
    for (int d = lane; d < D_; d += 64) {
        sf += b2f(q0[d]) * b2f(k1[d]);
        sb += b2f(q1[d]) * b2f(k0[d]);
    }
    #pragma unroll
    for (int off = 32; off > 0; off >>= 1) {
        sf += __shfl_xor(sf, off);
        sb += __shfl_xor(sb, off);
    }
    if (lane == 0) {
        sf *= (1.f / 64.f); sb *= (1.f / 64.f);
        float ah = 0.5f * (1.f / (1.f + expf(-sf)) + 1.f / (1.f + expf(-sb)));
        float a = ah;
        if (lidx[0] != 0) { float p = prev[gid]; a = p + (1.f - p) * ah; }
        a_out[gid] = a;
    }
}

// ---------------- L[b,k] = sum_{t<k} log a[b,t] ----------------
__global__ void cumsum_k(const float* __restrict__ a_f, float* __restrict__ L) {
    int b = blockIdx.x;
    int lane = threadIdx.x;
    float lg[8]; float s = 0.f;
    #pragma unroll
    for (int r = 0; r < 8; ++r) {
        int t = lane * 8 + r;
        lg[r] = (t < S_ - 1) ? logf(fmaxf(a_f[b * (S_ - 1) + t], 1e-35f)) : 0.f;
        s += lg[r];
    }
    float incl = s;
    #pragma unroll
    for (int off = 1; off < 64; off <<= 1) {
        float n = __shfl_up(incl, off);
        if (lane >= off) incl += n;
    }
    float run = incl - s;
    #pragma unroll
    for (int r = 0; r < 8; ++r) {
        L[b * S_ + lane * 8 + r] = run;
        run += lg[r];
    }
}

// ---------------- fused attention: QK^T -> softmax -> C-mask -> PV ----------
// Swapped MFMA (A=K rows, B=Q rows): lane(r16,kq) reg r holds
// S[q = q0+wave*16+r16][j = jt*16+kq*4+r]  -> softmax is lane-local over j.
// K/Q/V fragments read DIRECT from global (L2-resident; no LDS staging,
// no inter-phase barriers) -> 10 KB LDS. Bound (256,2): no VGPR spill.
__launch_bounds__(256, 2)
__global__ void attn_fused(const u16* __restrict__ QKV, const u16* __restrict__ Vt,
                           const float* __restrict__ L,
                           float* __restrict__ Attn, u16* __restrict__ ctx)
{
    const int ST = 3 * D_;
    __shared__ __align__(16) u16 Pt_all[4 * 16 * 64];   // 8 KB (per-wave P tiles)
    __shared__ float Lsh[S_];                            // 2 KB
    int bh = blockIdx.y; int b = bh / H_, h = bh % H_;
    int q0 = blockIdx.x * 64;
    int tid = threadIdx.x;
    int wave = tid >> 6, lane = tid & 63;
    int r16 = lane & 15, kq = lane >> 4;

    for (int j = tid; j < S_; j += 256) Lsh[j] = L[b * S_ + j];

    // Q fragments direct from global (B-operand of swapped MFMA)
    int arow = wave * 16 + r16;
    const u16* qp = &QKV[(size_t)(b * S_ + q0 + arow) * ST + h * DH_];
    bf16x8 a0 = *(const bf16x8*)(qp + kq * 8);
    bf16x8 a1 = *(const bf16x8*)(qp + 32 + kq * 8);

    // QK^T: K fragments direct from global (A-operand rows)
    const u16* kbase = &QKV[(size_t)(b * S_) * ST + D_ + h * DH_];
    f32x4 acc[32];
    #pragma unroll
    for (int jt = 0; jt < 32; ++jt) {
        const u16* kp = kbase + (size_t)(jt * 16 + r16) * ST;
        bf16x8 b0 = *(const bf16x8*)(kp + kq * 8);
        bf16x8 b1 = *(const bf16x8*)(kp + 32 + kq * 8);
        f32x4 z = {0.f, 0.f, 0.f, 0.f};
        z = __builtin_amdgcn_mfma_f32_16x16x32_bf16(b0, a0, z, 0, 0, 0);   // swapped
        acc[jt] = __builtin_amdgcn_mfma_f32_16x16x32_bf16(b1, a1, z, 0, 0, 0);
    }

    // softmax stats: per-lane over 128 j + reduce across kq lanes (bits 4,5)
    float mx = -1e30f;
    #pragma unroll
    for (int jt = 0; jt < 32; ++jt)
        #pragma unroll
        for (int r = 0; r < 4; ++r)
            mx = fmaxf(mx, acc[jt][r] * 0.125f);
    mx = fmaxf(mx, __shfl_xor(mx, 16));
    mx = fmaxf(mx, __shfl_xor(mx, 32));
    float sum = 0.f;
    #pragma unroll
    for (int jt = 0; jt < 32; ++jt)
        #pragma unroll
        for (int r = 0; r < 4; ++r) {
            float e = __expf(acc[jt][r] * 0.125f - mx);
            acc[jt][r] = e; sum += e;
        }
    sum += __shfl_xor(sum, 16);
    sum += __shfl_xor(sum, 32);
    float inv = 1.f / sum;
    int qg = q0 + wave * 16 + r16;
    __syncthreads();              // Lsh ready (only barrier in kernel)
    float Lq = Lsh[qg];

    // pass 3: per 64-j chunk: normalize+C-mask, write Attn (f32x4), pack P
    // into per-wave swizzled LDS tile, PV MFMA with V^T direct from global.
    u16* Pt = &Pt_all[wave * 1024];
    const u16* vtb = Vt + (size_t)bh * DH_ * S_;
    size_t obase = (size_t)bh * S_ * S_ + (size_t)qg * S_;
    f32x4 accpv[4] = {};
    #pragma unroll
    for (int c = 0; c < 8; ++c) {
        #pragma unroll
        for (int jt4 = 0; jt4 < 4; ++jt4) {
            int jt = c * 4 + jt4;
            int j0c = jt * 16 + kq * 4;
            f32x4 Ljv = *(const f32x4*)&Lsh[j0c];
            f32x4 pv;
            #pragma unroll
            for (int r = 0; r < 4; ++r) {
                int j = j0c + r;
                float dr = (j >= qg) ? (Ljv[r] - Lq) : (Lq - Ljv[r]);
                pv[r] = acc[jt][r] * inv * __expf(fminf(dr, 0.f));
            }
            *(f32x4*)&Attn[obase + j0c] = pv;
            u32 lo = (u32)f2b(pv[0]) | ((u32)f2b(pv[1]) << 16);
            u32 hi = (u32)f2b(pv[2]) | ((u32)f2b(pv[3]) << 16);
            int jloc = jt4 * 16 + kq * 4;
            u32x2 pk; pk.x = lo; pk.y = hi;
            *(u32x2*)&Pt[r16 * 64 + (jloc ^ ((r16 & 7) << 3))] = pk;
        }
        #pragma unroll
        for (int ks = 0; ks < 2; ++ks) {
            bf16x8 ap = *(const bf16x8*)&Pt[r16 * 64 + ((ks * 32 + kq * 8) ^ ((r16 & 7) << 3))];
            #pragma unroll
            for (int n = 0; n < 4; ++n) {
                int d = n * 16 + r16;
                bf16x8 bv = *(const bf16x8*)&vtb[(size_t)d * S_ + c * 64 + ks * 32 + kq * 8];
                accpv[n] = __builtin_amdgcn_mfma_f32_16x16x32_bf16(ap, bv, accpv[n], 0, 0, 0);
            }
        }
    }
    // epilogue: ctx[q][d], q = q0+wave*16+kq*4+r, d = n*16+r16
    int qq = q0 + wave * 16 + kq * 4;
    #pragma unroll
    for (int n = 0; n < 4; ++n) {
        int d = n * 16 + r16;
        #pragma unroll
        for (int r = 0; r < 4; ++r)
            ctx[(size_t)(b * S_ + qq + r) * D_ + h * DH_ + d] = f2b(accpv[n][r]);
    }
}

// ---------------- launcher ----------------
extern "C" void kernel_launch(void* const* d_in, const int* in_sizes, int n_in,
                              void* d_out, int out_size, void* d_ws, size_t ws_size,
                              hipStream_t stream) {
    const float* x    = (const float*)d_in[0];
    const float* prev = (const float*)d_in[2];
    const float* Wqn = (const float*)d_in[3];  const float* bqn = (const float*)d_in[4];
    const float* Wkn = (const float*)d_in[5];  const float* bkn = (const float*)d_in[6];
    const float* Wq  = (const float*)d_in[7];  const float* bq  = (const float*)d_in[8];
    const float* Wk  = (const float*)d_in[9];  const float* bk  = (const float*)d_in[10];
    const float* Wv  = (const float*)d_in[11]; const float* bv  = (const float*)d_in[12];
    const float* Wo  = (const float*)d_in[13]; const float* bo  = (const float*)d_in[14];
    const float* W1  = (const float*)d_in[15]; const float* b1  = (const float*)d_in[16];
    const float* W2  = (const float*)d_in[17]; const float* b2  = (const float*)d_in[18];
    const float* g1  = (const float*)d_in[19]; const float* be1 = (const float*)d_in[20];
    const float* g2  = (const float*)d_in[21]; const float* be2 = (const float*)d_in[22];
    const int* lidx = (const int*)d_in[23];

    char* ws = (char*)d_ws;
    size_t off = 0;
    auto alloc = [&](size_t bytes) -> void* {
        void* p = ws + off; off += (bytes + 255) & ~(size_t)255; return p;
    };
    const size_t DDe = (size_t)D_ * D_;
    u16* WT_nk  = (u16*)alloc(2 * DDe * 2);
    u16* WT_qkv = (u16*)alloc(3 * DDe * 2);
    u16* WT_o   = (u16*)alloc(DDe * 2);
    u16* W1T    = (u16*)alloc((size_t)FF_ * D_ * 2);
    u16* W2T    = (u16*)alloc((size_t)FF_ * D_ * 2);
    float* bias_nk  = (float*)alloc(2 * D_ * 4);
    float* bias_qkv = (float*)alloc(3 * D_ * 4);
    u16* xb    = (u16*)alloc((size_t)M_ * D_ * 2);       // reused as Vt
    u16* nk_b  = (u16*)alloc((size_t)M_ * 2 * D_ * 2);
    u16* qkv_b = (u16*)alloc((size_t)M_ * 3 * D_ * 2);
    float* L_f = (float*)alloc((size_t)B_ * S_ * 4);
    u16* xn_b  = (u16*)alloc((size_t)M_ * D_ * 2);       // reused as xn2_b
    u16* ctx_b = (u16*)alloc((size_t)M_ * D_ * 2);
    float* x1_f = (float*)alloc((size_t)M_ * D_ * 4);
    float* parts = (float*)alloc((size_t)4 * M_ * D_ * 4);  // split-K partials
    u16* h_b = nk_b;      // FFN hidden aliases nk_b..qkv_b (dead by then)
    u16* xn2_b = xn_b;
    u16* Vt = xb;         // xb dead after nk gemm; qkv gemm writes V here

    float* out0     = (float*)d_out;                       // [B,S,D]
    float* out_a    = out0 + (size_t)M_ * D_;              // [B,S-1]
    float* out_attn = out_a + (size_t)B_ * (S_ - 1);       // [B,H,S,S]

    dim3 tb(32, 8);
    // LN1 + raw cast of x in one pass
    ln_cast_k<<<M_ / 4, 256, 0, stream>>>(x, g1, be1, xn_b, xb);
    transpose_all<<<8064, tb, 0, stream>>>(
        Wqn, Wkn, Wq, Wk, Wv, Wo, W1, W2,
        WT_nk, WT_qkv, WT_o, W1T, W2T);
    bias_concat<<<15, 256, 0, stream>>>(bqn, bkn, bq, bk, bv, bias_nk, bias_qkv);

    // nk = x @ [Wqn|Wkn]  (full-K)
    gemm_mfma<<<dim3(2*D_/128, M_/128), 256, 0, stream>>>(
        xb, WT_nk, bias_nk, nullptr, nk_b, nullptr, nullptr, 2*D_, D_, D_, 0, 0);
    affinity_k<<<(B_ * (S_ - 1) + 3) / 4, 256, 0, stream>>>(nk_b, prev, lidx, out_a);
    cumsum_k<<<B_, 64, 0, stream>>>(out_a, L_f);

    // qkv = xn @ [Wq|Wk|Wv]  (full-K); V columns written transposed to Vt
    gemm_mfma<<<dim3(3*D_/128, M_/128), 256, 0, stream>>>(
        xn_b, WT_qkv, bias_qkv, nullptr, qkv_b, nullptr, Vt, 3*D_, D_, D_, 0, 0);

    attn_fused<<<dim3(S_/64, B_*H_), 256, 0, stream>>>(qkv_b, Vt, L_f, out_attn, ctx_b);

    // x1 = x + bo + ctx@Wo  (split-K=2) then LN2, fused reduce+LN
    gemm_mfma<<<dim3(D_/128, M_/128, 2), 256, 0, stream>>>(
        ctx_b, WT_o, nullptr, nullptr, nullptr, parts, nullptr, D_, D_, D_/2, 0, 1);
    reduce_ln_k<<<M_ / 4, 256, 0, stream>>>(parts, 2, x, bo, g2, be2, x1_f, xn2_b);
    // h = relu(xn2 @ W1 + b1)  (full-K)
    gemm_mfma<<<dim3(FF_/128, M_/128), 256, 0, stream>>>(
        xn2_b, W1T, b1, nullptr, h_b, nullptr, nullptr, FF_, D_, D_, 1, 0);
    // out = x1 + b2 + h@W2  (split-K=2)
    gemm_mfma<<<dim3(D_/128, M_/128, 2), 256, 0, stream>>>(
        h_b, W2T, nullptr, nullptr, nullptr, parts, nullptr, D_, FF_, FF_/2, 0, 1);
    reduce_k<<<(M_ * D_ / 4 + 255) / 256, 256, 0, stream>>>(
        parts, 2, x1_f, b2, out0, D_, M_ * D_ / 4);
}

// Round 9
// 422.380 us; speedup vs baseline: 1.1041x; 1.0610x over previous
//
#include <hip/hip_runtime.h>
#include <math.h>

// HierarchicalAttentionEncoderLayer — inputs f32, outputs f32, internals bf16.
// R9: revert attn_fused to the R2 STAGED structure (measured 77 µs, VGPR=152,
// no spill) — the direct-global v2 regressed (92 µs, acc pushed to AGPR/scratch).
// Single delta vs R2 attn: expf -> __expf. Launcher keeps R6/R8 fusions.
#define B_  8
#define S_  512
#define D_  768
#define H_  12
#define DH_ 64
#define FF_ 3072
#define M_  (B_ * S_)   // 4096 rows

typedef unsigned short u16;
typedef unsigned int   u32;
typedef __bf16  bf16x8 __attribute__((ext_vector_type(8)));
typedef float   f32x4  __attribute__((ext_vector_type(4)));
typedef unsigned short u16x4 __attribute__((ext_vector_type(4)));
typedef unsigned int   u32x2 __attribute__((ext_vector_type(2)));

__device__ __forceinline__ float b2f(u16 h) {
    union { u32 u; float f; } v; v.u = ((u32)h) << 16; return v.f;
}
__device__ __forceinline__ u16 f2b(float f) {
    union { u32 u; float f; } v; v.f = f;
    u32 u = v.u;
    u32 r = (u + 0x7FFFu + ((u >> 16) & 1u)) >> 16;   // RTNE
    return (u16)r;
}

// async 16B global->LDS (m97 pattern); dst must be lane-contiguous per wave
__device__ __forceinline__ void gload16(const void* g, void* l) {
    __builtin_amdgcn_global_load_lds(
        (const __attribute__((address_space(1))) void*)g,
        (__attribute__((address_space(3))) void*)l, 16, 0, 0);
}

// ---------------- ALL weight transposes in one launch ----------------
// tiles: 6 x (768x768) = 3456, W1 (768x3072 -> 96x24) = 2304, W2 (3072x768) = 2304
__global__ void transpose_all(const float* Wqn, const float* Wkn, const float* Wq,
                              const float* Wk, const float* Wv, const float* Wo,
                              const float* W1, const float* W2,
                              u16* WT_nk, u16* WT_qkv, u16* WT_o,
                              u16* W1T, u16* W2T)
{
    __shared__ u16 tile[32][33];
    int t = blockIdx.x;
    const float* W; u16* WT; int R, C, bx, by;
    if (t < 3456) {
        int z = t / 576, rem = t % 576;
        bx = rem % 24; by = rem / 24; R = D_; C = D_;
        W  = (z == 0) ? Wqn : (z == 1) ? Wkn : (z == 2) ? Wq
           : (z == 3) ? Wk  : (z == 4) ? Wv  : Wo;
        const size_t DDe = (size_t)D_ * D_;
        WT = (z == 0) ? WT_nk : (z == 1) ? WT_nk + DDe : (z == 2) ? WT_qkv
           : (z == 3) ? WT_qkv + DDe : (z == 4) ? WT_qkv + 2 * DDe : WT_o;
    } else if (t < 5760) {
        int rem = t - 3456;
        bx = rem % 96; by = rem / 96; R = D_; C = FF_;
        W = W1; WT = W1T;
    } else {
        int rem = t - 5760;
        bx = rem % 24; by = rem / 24; R = FF_; C = D_;
        W = W2; WT = W2T;
    }
    int c0 = bx * 32, r0 = by * 32;
    int tx = threadIdx.x, ty = threadIdx.y;   // (32,8)
    #pragma unroll
    for (int j = 0; j < 32; j += 8)
        tile[ty + j][tx] = f2b(W[(size_t)(r0 + ty + j) * C + (c0 + tx)]);
    __syncthreads();
    #pragma unroll
    for (int j = 0; j < 32; j += 8)
        WT[(size_t)(c0 + ty + j) * R + (r0 + tx)] = tile[tx][ty + j];
}

// ---------------- bias concat ----------------
__global__ void bias_concat(const float* bqn, const float* bkn, const float* bq,
                            const float* bk, const float* bv,
                            float* bias_nk, float* bias_qkv)
{
    int i = blockIdx.x * 256 + threadIdx.x;    // 0..3839
    if (i < 768)       bias_nk[i] = bqn[i];
    else if (i < 1536) bias_nk[i] = bkn[i - 768];
    else if (i < 2304) bias_qkv[i - 1536] = bq[i - 1536];
    else if (i < 3072) bias_qkv[i - 1536] = bk[i - 2304];
    else if (i < 3840) bias_qkv[i - 1536] = bv[i - 3072];
}

// ---------------- MFMA GEMM, BK=64, global_load_lds, XOR-swizzled LDS ------
// split=0: C = A·BT + bias (+relu) -> Cb bf16 / Cf f32; if VtOut, columns
//          cg in [2D,3D) are written TRANSPOSED per head to VtOut instead.
// split=1: partial A·BT (k-slice blockIdx.z) streamed to Cf + z*M_*N (f32)
__launch_bounds__(256)
__global__ void gemm_mfma(const u16* __restrict__ A, const u16* __restrict__ BT,
                          const float* __restrict__ bias, const float* __restrict__ res,
                          u16* __restrict__ Cb, float* __restrict__ Cf,
                          u16* __restrict__ VtOut,
                          int N, int K, int klen, int relu, int split)
{
    __shared__ __align__(16) u16 As[128 * 64];
    __shared__ __align__(16) u16 Bs[128 * 64];
    int tid = threadIdx.x;
    int wave = tid >> 6, lane = tid & 63;
    int m0 = blockIdx.y * 128, n0 = blockIdx.x * 128;
    int kbeg = blockIdx.z * klen;
    int wm = (wave >> 1) * 64, wn = (wave & 1) * 64;
    int r16 = lane & 15, kq = lane >> 4;
    f32x4 acc[4][4] = {};
    for (int k0 = 0; k0 < klen; k0 += 64) {
        #pragma unroll
        for (int i = 0; i < 4; ++i) {
            int cid = i * 256 + tid;          // 1024 chunks of 8 elems
            int row = cid >> 3, phys = cid & 7, logc = phys ^ (row & 7);
            gload16(&A [(size_t)(m0 + row) * K + kbeg + k0 + logc * 8], &As[cid * 8]);
            gload16(&BT[(size_t)(n0 + row) * K + kbeg + k0 + logc * 8], &Bs[cid * 8]);
        }
        __syncthreads();
        #pragma unroll
        for (int ks = 0; ks < 2; ++ks) {
            bf16x8 af[4], bfr[4];
            #pragma unroll
            for (int i = 0; i < 4; ++i) {
                int row = wm + i * 16 + r16;
                af[i] = *(const bf16x8*)&As[row * 64 + (((ks * 4 + kq) ^ (row & 7)) * 8)];
            }
            #pragma unroll
            for (int j = 0; j < 4; ++j) {
                int row = wn + j * 16 + r16;
                bfr[j] = *(const bf16x8*)&Bs[row * 64 + (((ks * 4 + kq) ^ (row & 7)) * 8)];
            }
            #pragma unroll
            for (int i = 0; i < 4; ++i)
                #pragma unroll
                for (int j = 0; j < 4; ++j)
                    acc[i][j] = __builtin_amdgcn_mfma_f32_16x16x32_bf16(
                        af[i], bfr[j], acc[i][j], 0, 0, 0);
        }
        __syncthreads();
    }
    if (split) {
        float* Pf = Cf + (size_t)blockIdx.z * M_ * N;
        #pragma unroll
        for (int i = 0; i < 4; ++i) {
            int rg = m0 + wm + i * 16 + kq * 4;
            #pragma unroll
            for (int j = 0; j < 4; ++j) {
                int cg = n0 + wn + j * 16 + r16;
                #pragma unroll
                for (int r = 0; r < 4; ++r)
                    Pf[(size_t)(rg + r) * N + cg] = acc[i][j][r];
            }
        }
        return;
    }
    #pragma unroll
    for (int i = 0; i < 4; ++i) {
        int rg = m0 + wm + i * 16 + kq * 4;
        #pragma unroll
        for (int j = 0; j < 4; ++j) {
            int cg = n0 + wn + j * 16 + r16;
            float bc = bias[cg];
            if (VtOut && cg >= 2 * D_) {
                // V column: write transposed, Vt[(bh*64+d)*512 + s]
                int hd = cg - 2 * D_;                      // 0..767
                int bh = (rg >> 9) * H_ + (hd >> 6);
                int d  = hd & 63;
                u16* vp = VtOut + ((size_t)bh * DH_ + d) * S_ + (rg & 511);
                #pragma unroll
                for (int r = 0; r < 4; ++r)
                    vp[r] = f2b(acc[i][j][r] + bc);
            } else {
                #pragma unroll
                for (int r = 0; r < 4; ++r) {
                    float v = acc[i][j][r] + bc;
                    if (relu) v = fmaxf(v, 0.f);
                    size_t off = (size_t)(rg + r) * N + cg;
                    if (Cb) Cb[off] = f2b(v);
                    if (Cf) Cf[off] = v;
                }
            }
        }
    }
}

// ---------------- reduce: out = res + bias + sum parts (final, no LN) ------
__global__ void reduce_k(const float* __restrict__ parts, int KS,
                         const float* __restrict__ res, const float* __restrict__ bias,
                         float* __restrict__ out, int N, int n4)
{
    int i4 = blockIdx.x * 256 + threadIdx.x;
    if (i4 >= n4) return;
    size_t base = (size_t)i4 * 4;
    int col = (int)(base % N);
    f32x4 acc = *(const f32x4*)(res + base);
    f32x4 bv = *(const f32x4*)(bias + col);
    acc.x += bv.x; acc.y += bv.y; acc.z += bv.z; acc.w += bv.w;
    const size_t MN = (size_t)M_ * N;
    for (int s = 0; s < KS; ++s) {
        f32x4 p = *(const f32x4*)(parts + s * MN + base);
        acc.x += p.x; acc.y += p.y; acc.z += p.z; acc.w += p.w;
    }
    *(f32x4*)(out + base) = acc;
}

// ---------------- reduce + LayerNorm fused (x1 path) ----------------
__global__ void reduce_ln_k(const float* __restrict__ parts, int KS,
                            const float* __restrict__ res, const float* __restrict__ bias,
                            const float* __restrict__ g, const float* __restrict__ be,
                            float* __restrict__ Xout, u16* __restrict__ Y)
{
    int row  = blockIdx.x * 4 + (threadIdx.x >> 6);
    int lane = threadIdx.x & 63;
    size_t rb = (size_t)row * D_;
    f32x4 xv[3];
    float s = 0.f, sq = 0.f;
    #pragma unroll
    for (int t = 0; t < 3; ++t) {
        int d = lane * 4 + t * 256;
        f32x4 a  = *(const f32x4*)(res + rb + d);
        f32x4 bv = *(const f32x4*)(bias + d);
        a.x += bv.x; a.y += bv.y; a.z += bv.z; a.w += bv.w;
        for (int ss = 0; ss < KS; ++ss) {
            f32x4 p = *(const f32x4*)(parts + (size_t)ss * M_ * D_ + rb + d);
            a.x += p.x; a.y += p.y; a.z += p.z; a.w += p.w;
        }
        *(f32x4*)(Xout + rb + d) = a;
        xv[t] = a;
        #pragma unroll
        for (int e = 0; e < 4; ++e) { float v = a[e]; s += v; sq += v * v; }
    }
    #pragma unroll
    for (int off = 32; off > 0; off >>= 1) {
        s  += __shfl_xor(s, off);
        sq += __shfl_xor(sq, off);
    }
    float m  = s * (1.f / (float)D_);
    float var = sq * (1.f / (float)D_) - m * m;
    float rs = rsqrtf(var + 1e-5f);
    u16* yr = Y + rb;
    #pragma unroll
    for (int t = 0; t < 3; ++t) {
        int d = lane * 4 + t * 256;
        f32x4 gv = *(const f32x4*)(g + d);
        f32x4 bv = *(const f32x4*)(be + d);
        u16x4 o;
        #pragma unroll
        for (int e = 0; e < 4; ++e)
            o[e] = f2b((xv[t][e] - m) * rs * gv[e] + bv[e]);
        *(u16x4*)(yr + d) = o;
    }
}

// ---------------- LayerNorm + optional raw cast output (reads x once) ------
__global__ void ln_cast_k(const float* __restrict__ X, const float* __restrict__ g,
                          const float* __restrict__ be, u16* __restrict__ Y,
                          u16* __restrict__ Ycast)
{
    int row  = blockIdx.x * 4 + (threadIdx.x >> 6);
    int lane = threadIdx.x & 63;
    const float* xr = X + (size_t)row * D_;
    f32x4 xv[3];
    float s = 0.f, sq = 0.f;
    #pragma unroll
    for (int t = 0; t < 3; ++t) {
        xv[t] = *(const f32x4*)(xr + lane * 4 + t * 256);
        #pragma unroll
        for (int e = 0; e < 4; ++e) { float v = xv[t][e]; s += v; sq += v * v; }
    }
    if (Ycast) {
        u16* yc = Ycast + (size_t)row * D_;
        #pragma unroll
        for (int t = 0; t < 3; ++t) {
            u16x4 o;
            #pragma unroll
            for (int e = 0; e < 4; ++e) o[e] = f2b(xv[t][e]);
            *(u16x4*)(yc + lane * 4 + t * 256) = o;
        }
    }
    #pragma unroll
    for (int off = 32; off > 0; off >>= 1) {
        s  += __shfl_xor(s, off);
        sq += __shfl_xor(sq, off);
    }
    float m  = s * (1.f / (float)D_);
    float var = sq * (1.f / (float)D_) - m * m;
    float rs = rsqrtf(var + 1e-5f);
    u16* yr = Y + (size_t)row * D_;
    #pragma unroll
    for (int t = 0; t < 3; ++t) {
        int d = lane * 4 + t * 256;
        f32x4 gv = *(const f32x4*)(g + d);
        f32x4 bv = *(const f32x4*)(be + d);
        u16x4 o;
        #pragma unroll
        for (int e = 0; e < 4; ++e)
            o[e] = f2b((xv[t][e] - m) * rs * gv[e] + bv[e]);
        *(u16x4*)(yr + d) = o;
    }
}

// ---------------- affinity: a[b,i] from fused nk buffer (stride 1536) -------
__global__ void affinity_k(const u16* __restrict__ nk,
                           const float* __restrict__ prev, const int* __restrict__ lidx,
                           float* __restrict__ a_out)
{
    const int ST = 2 * D_;
    int gid  = blockIdx.x * 4 + (threadIdx.x >> 6);
    int lane = threadIdx.x & 63;
    if (gid >= B_ * (S_ - 1)) return;
    int b = gid / (S_ - 1), i = gid % (S_ - 1);
    const u16* q0 = nk + (size_t)(b * S_ + i)     * ST;
    const u16* q1 = nk + (size_t)(b * S_ + i + 1) * ST;
    const u16* k0 = q0 + D_;
    const u16* k1 = q1 + D_;
    float sf = 0.f, sb = 0.f;
    for (int d = lane; d < D_; d += 64) {
        sf += b2f(q0[d]) * b2f(k1[d]);
        sb += b2f(q1[d]) * b2f(k0[d]);
    }
    #pragma unroll
    for (int off = 32; off > 0; off >>= 1) {
        sf += __shfl_xor(sf, off);
        sb += __shfl_xor(sb, off);
    }
    if (lane == 0) {
        sf *= (1.f / 64.f); sb *= (1.f / 64.f);
        float ah = 0.5f * (1.f / (1.f + expf(-sf)) + 1.f / (1.f + expf(-sb)));
        float a = ah;
        if (lidx[0] != 0) { float p = prev[gid]; a = p + (1.f - p) * ah; }
        a_out[gid] = a;
    }
}

// ---------------- L[b,k] = sum_{t<k} log a[b,t] ----------------
__global__ void cumsum_k(const float* __restrict__ a_f, float* __restrict__ L) {
    int b = blockIdx.x;
    int lane = threadIdx.x;
    float lg[8]; float s = 0.f;
    #pragma unroll
    for (int r = 0; r < 8; ++r) {
        int t = lane * 8 + r;
        lg[r] = (t < S_ - 1) ? logf(fmaxf(a_f[b * (S_ - 1) + t], 1e-35f)) : 0.f;
        s += lg[r];
    }
    float incl = s;
    #pragma unroll
    for (int off = 1; off < 64; off <<= 1) {
        float n = __shfl_up(incl, off);
        if (lane >= off) incl += n;
    }
    float run = incl - s;
    #pragma unroll
    for (int r = 0; r < 8; ++r) {
        L[b * S_ + lane * 8 + r] = run;
        run += lg[r];
    }
}

// ---------------- fused attention: QK^T -> softmax -> C-mask -> PV ----------
// R2 STAGED structure (measured 77 µs, VGPR=152, no spill):
// K (512x64) + Q (64x64) staged via gload16 (swizzled); swapped MFMA so
// S[q][j] is lane-local over j; V^T staged into Ks region after QK; per-wave
// Pt tile overlays Qs. Only change vs R2: expf -> __expf.
__launch_bounds__(256)
__global__ void attn_fused(const u16* __restrict__ QKV, const u16* __restrict__ Vt,
                           const float* __restrict__ L,
                           float* __restrict__ Attn, u16* __restrict__ ctx)
{
    const int ST = 3 * D_;
    __shared__ __align__(16) u16 Ks[S_ * 64];   // 64 KB: K tile, then V^T[64][512]
    __shared__ __align__(16) u16 Qs[64 * 64];   // 8 KB: Q tile, then per-wave Pt
    __shared__ float Lsh[S_];
    int bh = blockIdx.y; int b = bh / H_, h = bh % H_;
    int q0 = blockIdx.x * 64;
    int tid = threadIdx.x;
    int wave = tid >> 6, lane = tid & 63;
    int r16 = lane & 15, kq = lane >> 4;

    // async staging: Q (64x64) + K (512x64), pre-swizzled by (row&7)
    #pragma unroll
    for (int i = 0; i < 2; ++i) {
        int cid = i * 256 + tid;
        int row = cid >> 3, logc = (cid & 7) ^ (row & 7);
        gload16(&QKV[(size_t)(b * S_ + q0 + row) * ST + h * DH_ + logc * 8], &Qs[cid * 8]);
    }
    #pragma unroll
    for (int i = 0; i < 16; ++i) {
        int cid = i * 256 + tid;
        int row = cid >> 3, logc = (cid & 7) ^ (row & 7);
        gload16(&QKV[(size_t)(b * S_ + row) * ST + D_ + h * DH_ + logc * 8], &Ks[cid * 8]);
    }
    for (int j = tid; j < S_; j += 256) Lsh[j] = L[b * S_ + j];
    __syncthreads();

    int arow = wave * 16 + r16;
    bf16x8 a0 = *(const bf16x8*)&Qs[arow * 64 + (((kq)     ^ (arow & 7)) * 8)];
    bf16x8 a1 = *(const bf16x8*)&Qs[arow * 64 + (((4 + kq) ^ (arow & 7)) * 8)];
    f32x4 acc[32];
    #pragma unroll
    for (int jt = 0; jt < 32; ++jt) {
        int brow = jt * 16 + r16;
        bf16x8 b0 = *(const bf16x8*)&Ks[brow * 64 + (((kq)     ^ (brow & 7)) * 8)];
        bf16x8 b1 = *(const bf16x8*)&Ks[brow * 64 + (((4 + kq) ^ (brow & 7)) * 8)];
        f32x4 z = {0.f, 0.f, 0.f, 0.f};
        z = __builtin_amdgcn_mfma_f32_16x16x32_bf16(b0, a0, z, 0, 0, 0);   // swapped
        acc[jt] = __builtin_amdgcn_mfma_f32_16x16x32_bf16(b1, a1, z, 0, 0, 0);
    }
    __syncthreads();   // all Ks/Qs reads complete

    // stage V^T (64 x 512) into Ks region, XOR-swizzled ((d&7)<<3 on u16 idx)
    const u16* vtb = Vt + (size_t)bh * DH_ * S_;
    #pragma unroll
    for (int i = 0; i < 16; ++i) {
        int cid = i * 256 + tid;
        int d = cid >> 6, p = cid & 63, l = p ^ (d & 7);
        gload16(&vtb[(size_t)d * S_ + l * 8], &Ks[cid * 8]);
    }

    // softmax stats: per-lane over 128 j + reduce across kq lanes (bits 4,5)
    float mx = -1e30f;
    #pragma unroll
    for (int jt = 0; jt < 32; ++jt)
        #pragma unroll
        for (int r = 0; r < 4; ++r)
            mx = fmaxf(mx, acc[jt][r] * 0.125f);
    mx = fmaxf(mx, __shfl_xor(mx, 16));
    mx = fmaxf(mx, __shfl_xor(mx, 32));
    float sum = 0.f;
    #pragma unroll
    for (int jt = 0; jt < 32; ++jt)
        #pragma unroll
        for (int r = 0; r < 4; ++r) {
            float e = __expf(acc[jt][r] * 0.125f - mx);
            acc[jt][r] = e; sum += e;
        }
    sum += __shfl_xor(sum, 16);
    sum += __shfl_xor(sum, 32);
    float inv = 1.f / sum;
    int qg = q0 + wave * 16 + r16;
    float Lq = Lsh[qg];
    __syncthreads();   // V^T staged (barrier drains vmcnt)

    // pass 3: per 64-j chunk: normalize+C-mask, write Attn (f32x4), pack P
    // into per-wave swizzled LDS tile, PV MFMA accumulate from LDS V^T.
    u16* Pt = &Qs[wave * 1024];          // 16 q x 64 j bf16, swizzled
    size_t obase = (size_t)bh * S_ * S_ + (size_t)qg * S_;
    f32x4 accpv[4] = {};
    #pragma unroll
    for (int c = 0; c < 8; ++c) {
        #pragma unroll
        for (int jt4 = 0; jt4 < 4; ++jt4) {
            int jt = c * 4 + jt4;
            int j0c = jt * 16 + kq * 4;
            f32x4 Ljv = *(const f32x4*)&Lsh[j0c];
            f32x4 pv;
            #pragma unroll
            for (int r = 0; r < 4; ++r) {
                int j = j0c + r;
                float dr = (j >= qg) ? (Ljv[r] - Lq) : (Lq - Ljv[r]);
                pv[r] = acc[jt][r] * inv * __expf(fminf(dr, 0.f));
            }
            *(f32x4*)&Attn[obase + j0c] = pv;
            u32 lo = (u32)f2b(pv[0]) | ((u32)f2b(pv[1]) << 16);
            u32 hi = (u32)f2b(pv[2]) | ((u32)f2b(pv[3]) << 16);
            int jloc = jt4 * 16 + kq * 4;
            u32x2 pk; pk.x = lo; pk.y = hi;
            *(u32x2*)&Pt[r16 * 64 + (jloc ^ ((r16 & 7) << 3))] = pk;
        }
        #pragma unroll
        for (int ks = 0; ks < 2; ++ks) {
            bf16x8 ap = *(const bf16x8*)&Pt[r16 * 64 + ((ks * 32 + kq * 8) ^ ((r16 & 7) << 3))];
            #pragma unroll
            for (int n = 0; n < 4; ++n) {
                int d = n * 16 + r16;
                bf16x8 bv = *(const bf16x8*)&Ks[d * 512 + ((c * 64 + ks * 32 + kq * 8) ^ ((d & 7) << 3))];
                accpv[n] = __builtin_amdgcn_mfma_f32_16x16x32_bf16(ap, bv, accpv[n], 0, 0, 0);
            }
        }
    }
    // epilogue: ctx[q][d], q = q0+wave*16+kq*4+r, d = n*16+r16
    int qq = q0 + wave * 16 + kq * 4;
    #pragma unroll
    for (int n = 0; n < 4; ++n) {
        int d = n * 16 + r16;
        #pragma unroll
        for (int r = 0; r < 4; ++r)
            ctx[(size_t)(b * S_ + qq + r) * D_ + h * DH_ + d] = f2b(accpv[n][r]);
    }
}

// ---------------- launcher ----------------
extern "C" void kernel_launch(void* const* d_in, const int* in_sizes, int n_in,
                              void* d_out, int out_size, void* d_ws, size_t ws_size,
                              hipStream_t stream) {
    const float* x    = (const float*)d_in[0];
    const float* prev = (const float*)d_in[2];
    const float* Wqn = (const float*)d_in[3];  const float* bqn = (const float*)d_in[4];
    const float* Wkn = (const float*)d_in[5];  const float* bkn = (const float*)d_in[6];
    const float* Wq  = (const float*)d_in[7];  const float* bq  = (const float*)d_in[8];
    const float* Wk  = (const float*)d_in[9];  const float* bk  = (const float*)d_in[10];
    const float* Wv  = (const float*)d_in[11]; const float* bv  = (const float*)d_in[12];
    const float* Wo  = (const float*)d_in[13]; const float* bo  = (const float*)d_in[14];
    const float* W1  = (const float*)d_in[15]; const float* b1  = (const float*)d_in[16];
    const float* W2  = (const float*)d_in[17]; const float* b2  = (const float*)d_in[18];
    const float* g1  = (const float*)d_in[19]; const float* be1 = (const float*)d_in[20];
    const float* g2  = (const float*)d_in[21]; const float* be2 = (const float*)d_in[22];
    const int* lidx = (const int*)d_in[23];

    char* ws = (char*)d_ws;
    size_t off = 0;
    auto alloc = [&](size_t bytes) -> void* {
        void* p = ws + off; off += (bytes + 255) & ~(size_t)255; return p;
    };
    const size_t DDe = (size_t)D_ * D_;
    u16* WT_nk  = (u16*)alloc(2 * DDe * 2);
    u16* WT_qkv = (u16*)alloc(3 * DDe * 2);
    u16* WT_o   = (u16*)alloc(DDe * 2);
    u16* W1T    = (u16*)alloc((size_t)FF_ * D_ * 2);
    u16* W2T    = (u16*)alloc((size_t)FF_ * D_ * 2);
    float* bias_nk  = (float*)alloc(2 * D_ * 4);
    float* bias_qkv = (float*)alloc(3 * D_ * 4);
    u16* xb    = (u16*)alloc((size_t)M_ * D_ * 2);       // reused as Vt
    u16* nk_b  = (u16*)alloc((size_t)M_ * 2 * D_ * 2);
    u16* qkv_b = (u16*)alloc((size_t)M_ * 3 * D_ * 2);
    float* L_f = (float*)alloc((size_t)B_ * S_ * 4);
    u16* xn_b  = (u16*)alloc((size_t)M_ * D_ * 2);       // reused as xn2_b
    u16* ctx_b = (u16*)alloc((size_t)M_ * D_ * 2);
    float* x1_f = (float*)alloc((size_t)M_ * D_ * 4);
    float* parts = (float*)alloc((size_t)4 * M_ * D_ * 4);  // split-K partials
    u16* h_b = nk_b;      // FFN hidden aliases nk_b..qkv_b (dead by then)
    u16* xn2_b = xn_b;
    u16* Vt = xb;         // xb dead after nk gemm; qkv gemm writes V here

    float* out0     = (float*)d_out;                       // [B,S,D]
    float* out_a    = out0 + (size_t)M_ * D_;              // [B,S-1]
    float* out_attn = out_a + (size_t)B_ * (S_ - 1);       // [B,H,S,S]

    dim3 tb(32, 8);
    // LN1 + raw cast of x in one pass
    ln_cast_k<<<M_ / 4, 256, 0, stream>>>(x, g1, be1, xn_b, xb);
    transpose_all<<<8064, tb, 0, stream>>>(
        Wqn, Wkn, Wq, Wk, Wv, Wo, W1, W2,
        WT_nk, WT_qkv, WT_o, W1T, W2T);
    bias_concat<<<15, 256, 0, stream>>>(bqn, bkn, bq, bk, bv, bias_nk, bias_qkv);

    // nk = x @ [Wqn|Wkn]  (full-K)
    gemm_mfma<<<dim3(2*D_/128, M_/128), 256, 0, stream>>>(
        xb, WT_nk, bias_nk, nullptr, nk_b, nullptr, nullptr, 2*D_, D_, D_, 0, 0);
    affinity_k<<<(B_ * (S_ - 1) + 3) / 4, 256, 0, stream>>>(nk_b, prev, lidx, out_a);
    cumsum_k<<<B_, 64, 0, stream>>>(out_a, L_f);

    // qkv = xn @ [Wq|Wk|Wv]  (full-K); V columns written transposed to Vt
    gemm_mfma<<<dim3(3*D_/128, M_/128), 256, 0, stream>>>(
        xn_b, WT_qkv, bias_qkv, nullptr, qkv_b, nullptr, Vt, 3*D_, D_, D_, 0, 0);

    attn_fused<<<dim3(S_/64, B_*H_), 256, 0, stream>>>(qkv_b, Vt, L_f, out_attn, ctx_b);

    // x1 = x + bo + ctx@Wo  (split-K=2) then LN2, fused reduce+LN
    gemm_mfma<<<dim3(D_/128, M_/128, 2), 256, 0, stream>>>(
        ctx_b, WT_o, nullptr, nullptr, nullptr, parts, nullptr, D_, D_, D_/2, 0, 1);
    reduce_ln_k<<<M_ / 4, 256, 0, stream>>>(parts, 2, x, bo, g2, be2, x1_f, xn2_b);
    // h = relu(xn2 @ W1 + b1)  (full-K)
    gemm_mfma<<<dim3(FF_/128, M_/128), 256, 0, stream>>>(
        xn2_b, W1T, b1, nullptr, h_b, nullptr, nullptr, FF_, D_, D_, 1, 0);
    // out = x1 + b2 + h@W2  (split-K=2)
    gemm_mfma<<<dim3(D_/128, M_/128, 2), 256, 0, stream>>>(
        h_b, W2T, nullptr, nullptr, nullptr, parts, nullptr, D_, FF_, FF_/2, 0, 1);
    reduce_k<<<(M_ * D_ / 4 + 255) / 256, 256, 0, stream>>>(
        parts, 2, x1_f, b2, out0, D_, M_ * D_ / 4);
}